// Round 1
// baseline (330.347 us; speedup 1.0000x reference)
//
#include <hip/hip_runtime.h>
#include <math.h>

#define TDIM 1026

// ---------------- Kernel 1: FE GEMM (A @ W_fe) + bias + relu + per-episode col stats ----
// A: rows 0..8191 train, 8192..16383 test (row = e*32+n). Tile 128x128, block 256, micro 8x8.
__global__ __launch_bounds__(256)
void k_fe(const float* __restrict__ Atr, const float* __restrict__ Ate,
          const float* __restrict__ Wfe, const float* __restrict__ bfe,
          float* __restrict__ Z, float* __restrict__ muT_te)
{
    __shared__ float lds[4224];          // Ast[16][132] + Bs[16][132]; reused as stats buf
    float* Ast = lds;
    float* Bs  = lds + 2112;

    const int tid = threadIdx.x;
    const int tx = tid & 15;             // col groups
    const int ty = tid >> 4;             // row groups (8 contiguous rows each)
    const int col0 = blockIdx.x * 128;
    const int row0 = blockIdx.y * 128;
    const float* A = (row0 < 8192) ? Atr : Ate;
    const int ar0 = (row0 < 8192) ? row0 : (row0 - 8192);

    float acc[8][8];
#pragma unroll
    for (int i = 0; i < 8; ++i)
#pragma unroll
        for (int j = 0; j < 8; ++j) acc[i][j] = 0.f;

    for (int k0 = 0; k0 < 512; k0 += 16) {
        // stage A tile (128 rows x 16 k) transposed into Ast[k][row]
#pragma unroll
        for (int s = 0; s < 2; ++s) {
            int u = tid + s * 256;
            int row = u >> 2, q = u & 3;
            float4 v = *(const float4*)(A + (size_t)(ar0 + row) * 512 + k0 + q * 4);
            Ast[(q * 4 + 0) * 132 + row] = v.x;
            Ast[(q * 4 + 1) * 132 + row] = v.y;
            Ast[(q * 4 + 2) * 132 + row] = v.z;
            Ast[(q * 4 + 3) * 132 + row] = v.w;
        }
        // stage B tile (16 k x 128 cols)
#pragma unroll
        for (int s = 0; s < 2; ++s) {
            int u = tid + s * 256;
            int kk = u >> 5, c8 = u & 31;
            float4 v = *(const float4*)(Wfe + (size_t)(k0 + kk) * 512 + col0 + c8 * 4);
            *(float4*)(Bs + kk * 132 + c8 * 4) = v;
        }
        __syncthreads();
#pragma unroll
        for (int kk = 0; kk < 16; ++kk) {
            float4 a0 = *(const float4*)(Ast + kk * 132 + ty * 8);
            float4 a1 = *(const float4*)(Ast + kk * 132 + ty * 8 + 4);
            float4 b0 = *(const float4*)(Bs + kk * 132 + tx * 4);        // cols tx*4..+3
            float4 b1 = *(const float4*)(Bs + kk * 132 + 64 + tx * 4);   // cols 64+tx*4..+3
            float av[8] = {a0.x, a0.y, a0.z, a0.w, a1.x, a1.y, a1.z, a1.w};
            float bv[8] = {b0.x, b0.y, b0.z, b0.w, b1.x, b1.y, b1.z, b1.w};
#pragma unroll
            for (int i = 0; i < 8; ++i)
#pragma unroll
                for (int j = 0; j < 8; ++j)
                    acc[i][j] = fmaf(av[i], bv[j], acc[i][j]);
        }
        __syncthreads();
    }

    // epilogue: bias + relu; per-thread (8-row) column sums; thread rows ty*8..ty*8+7 lie in
    // one episode (ep_local = ty>>2 since episode = 32 rows)
    float2* sbuf = (float2*)lds;   // [16][128]
#pragma unroll
    for (int j = 0; j < 8; ++j) {
        int cl = (j < 4) ? (tx * 4 + j) : (64 + tx * 4 + (j - 4));
        float b = bfe[col0 + cl];
        float s1 = 0.f, s2 = 0.f;
#pragma unroll
        for (int i = 0; i < 8; ++i) {
            float v = acc[i][j] + b;
            v = fmaxf(v, 0.f);
            s1 += v; s2 += v * v;
        }
        sbuf[ty * 128 + cl] = make_float2(s1, s2);
    }
    __syncthreads();
    // reduce across the 4 ty-subgroups of each episode; 4 eps x 128 cols = 512 outputs
    for (int idx = tid; idx < 512; idx += 256) {
        int ep = idx >> 7, cl = idx & 127;
        float S1 = 0.f, S2 = 0.f;
#pragma unroll
        for (int q = 0; q < 4; ++q) {
            float2 p = sbuf[(ep * 4 + q) * 128 + cl];
            S1 += p.x; S2 += p.y;
        }
        float mean = S1 * (1.f / 32.f);
        float var  = (S2 - 32.f * mean * mean) * (1.f / 31.f);   // ddof=1
        float sd   = sqrtf(fmaxf(var, 0.f));
        int e = (row0 >> 5) + ep;
        int f = col0 + cl;
        Z[(size_t)e * TDIM + 1 + f]   = mean;   // x col (1+f) mean
        Z[(size_t)e * TDIM + 514 + f] = sd;     // x col (1+f) std
        if (e >= 256) {
            int j2 = e - 256;
            muT_te[(size_t)(1 + f) * 256 + j2]   = mean;
            muT_te[(size_t)(514 + f) * 256 + j2] = sd;
        }
    }
}

// ---------------- Kernel 2: targets column stats (x col 0) ----------------
__global__ __launch_bounds__(256)
void k_tgt(const float* __restrict__ Ttr, const float* __restrict__ Tte,
           float* __restrict__ Z, float* __restrict__ muT_te)
{
    int e = blockIdx.x * 256 + threadIdx.x;    // 0..511
    if (e >= 512) return;
    const float* p = (e < 256) ? (Ttr + (size_t)e * 32) : (Tte + (size_t)(e - 256) * 32);
    float S1 = 0.f, S2 = 0.f;
#pragma unroll
    for (int n = 0; n < 32; ++n) { float v = p[n]; S1 += v; S2 += v * v; }
    float mean = S1 * (1.f / 32.f);
    float var  = (S2 - 32.f * mean * mean) * (1.f / 31.f);
    float sd   = sqrtf(fmaxf(var, 0.f));
    Z[(size_t)e * TDIM + 0]   = mean;
    Z[(size_t)e * TDIM + 513] = sd;
    if (e >= 256) {
        muT_te[(size_t)0 * 256 + (e - 256)]   = mean;
        muT_te[(size_t)513 * 256 + (e - 256)] = sd;
    }
}

// ---------------- Kernel 3: LV GEMM (Z @ W_lv + b) -> clip -> E=exp(lv), R=exp(-lv), H ----
// M=512, N=1026, K=1026. Tile 64x64, block 256, micro 4x4, K-tile 16 (zero-filled edges).
__global__ __launch_bounds__(256)
void k_lv(const float* __restrict__ Z, const float* __restrict__ Wlv,
          const float* __restrict__ blv,
          float* __restrict__ E_tr, float* __restrict__ R_tr,
          float* __restrict__ E_teT, float* __restrict__ R_teT,
          float* __restrict__ Hs_te)
{
    __shared__ float Ast[16 * 68];   // [k][row], stride 68
    __shared__ float Bs[16 * 68];    // [k][col], stride 68
    const int tid = threadIdx.x;
    const int tx = tid & 15;         // 4 cols each
    const int ty = tid >> 4;         // 4 rows each
    const int col0 = blockIdx.x * 64;
    const int row0 = blockIdx.y * 64;

    float acc[4][4];
#pragma unroll
    for (int i = 0; i < 4; ++i)
#pragma unroll
        for (int j = 0; j < 4; ++j) acc[i][j] = 0.f;

    for (int k0 = 0; k0 < TDIM; k0 += 16) {
        // stage A: 64 rows x 16 k (row stride 1026 is only 8B-aligned -> float2 loads)
        {
            int row = tid >> 2, kp = tid & 3;
            const float* src = Z + (size_t)(row0 + row) * TDIM + k0 + kp * 4;
            float x0 = 0.f, x1 = 0.f, x2 = 0.f, x3 = 0.f;
            if (k0 + kp * 4 + 1 < TDIM) { float2 v = *(const float2*)(src);     x0 = v.x; x1 = v.y; }
            if (k0 + kp * 4 + 3 < TDIM) { float2 v = *(const float2*)(src + 2); x2 = v.x; x3 = v.y; }
            Ast[(kp * 4 + 0) * 68 + row] = x0;
            Ast[(kp * 4 + 1) * 68 + row] = x1;
            Ast[(kp * 4 + 2) * 68 + row] = x2;
            Ast[(kp * 4 + 3) * 68 + row] = x3;
        }
        // stage B: 16 k x 64 cols (scalar, masked — W_lv rows are 4104B-strided/unaligned)
        {
            int kk = tid >> 4, cg = tid & 15;
#pragma unroll
            for (int c = 0; c < 4; ++c) {
                int col = col0 + cg * 4 + c;
                float v = 0.f;
                if (k0 + kk < TDIM && col < TDIM)
                    v = Wlv[(size_t)(k0 + kk) * TDIM + col];
                Bs[kk * 68 + cg * 4 + c] = v;
            }
        }
        __syncthreads();
#pragma unroll
        for (int kk = 0; kk < 16; ++kk) {
            float4 a = *(const float4*)(Ast + kk * 68 + ty * 4);
            float4 b = *(const float4*)(Bs + kk * 68 + tx * 4);
            float av[4] = {a.x, a.y, a.z, a.w};
            float bv[4] = {b.x, b.y, b.z, b.w};
#pragma unroll
            for (int i = 0; i < 4; ++i)
#pragma unroll
                for (int j = 0; j < 4; ++j)
                    acc[i][j] = fmaf(av[i], bv[j], acc[i][j]);
        }
        __syncthreads();
    }

    float hpart[4] = {0.f, 0.f, 0.f, 0.f};
#pragma unroll
    for (int i = 0; i < 4; ++i) {
        int r = row0 + ty * 4 + i;
#pragma unroll
        for (int j = 0; j < 4; ++j) {
            int c = col0 + tx * 4 + j;
            if (c < TDIM) {
                float lv = acc[i][j] + blv[c];
                lv = fminf(fmaxf(lv, -9.f), -2.f);
                float E = expf(lv);
                float R = expf(-lv);
                if (r < 256) {
                    E_tr[(size_t)r * TDIM + c] = E;
                    R_tr[(size_t)r * TDIM + c] = R;
                } else {
                    E_teT[(size_t)c * 256 + (r - 256)] = E;
                    R_teT[(size_t)c * 256 + (r - 256)] = R;
                    hpart[i] += lv;
                }
            }
        }
    }
    if (row0 >= 256) {   // uniform per block
        __syncthreads();
        float* hbuf = Ast;   // 64 x 16
#pragma unroll
        for (int i = 0; i < 4; ++i) hbuf[(ty * 4 + i) * 16 + tx] = hpart[i];
        __syncthreads();
        if (tid < 64) {
            float s = 0.f;
#pragma unroll
            for (int x = 0; x < 16; ++x) s += hbuf[tid * 16 + x];
            atomicAdd(Hs_te + (row0 - 256 + tid), s);
        }
    }
}

// ---------------- Kernel 4: pairwise partial sums -----------------------------
// S[i][j] = sum_t E1*R2 + E2*R1 + (m1-m2)^2*(R1+R2), split over 16 t-chunks of 65.
// grid (32 i-blocks x 16 t-chunks), block 256 = j. tr rows broadcast from LDS, te coalesced.
#define TCH 65
__global__ __launch_bounds__(256)
void k_pair(const float* __restrict__ Z, const float* __restrict__ E_tr,
            const float* __restrict__ R_tr, const float* __restrict__ muT_te,
            const float* __restrict__ E_teT, const float* __restrict__ R_teT,
            float* __restrict__ Sp)
{
    __shared__ float Lm[8 * 68], Le[8 * 68], Lr[8 * 68];
    const int tid = threadIdx.x;
    const int i0 = blockIdx.x * 8;
    const int t0 = blockIdx.y * TCH;
    const int tlen = min(TCH, TDIM - t0);

    if (tid < tlen) {
#pragma unroll
        for (int r = 0; r < 8; ++r) {
            size_t off = (size_t)(i0 + r) * TDIM + t0 + tid;
            Lm[r * 68 + tid] = Z[off];     // mu_tr
            Le[r * 68 + tid] = E_tr[off];
            Lr[r * 68 + tid] = R_tr[off];
        }
    }
    __syncthreads();

    float S[8];
#pragma unroll
    for (int r = 0; r < 8; ++r) S[r] = 0.f;
    const int j = tid;
    for (int tt = 0; tt < tlen; ++tt) {
        size_t o = (size_t)(t0 + tt) * 256 + j;
        float m2 = muT_te[o], e2 = E_teT[o], r2 = R_teT[o];
#pragma unroll
        for (int r = 0; r < 8; ++r) {
            float m1 = Lm[r * 68 + tt];
            float e1 = Le[r * 68 + tt];
            float r1 = Lr[r * 68 + tt];
            float d = m1 - m2;
            S[r] += e1 * r2 + e2 * r1 + d * d * (r1 + r2);
        }
    }
#pragma unroll
    for (int r = 0; r < 8; ++r)
        Sp[((size_t)blockIdx.y * 256 + i0 + r) * 256 + j] = S[r];
}

// ---------------- Kernel 5: row log_softmax + classes -------------------------
// v[i,j] = -(0.5*S + Hs_te[j]); row constants (H_tr, -T, 2C) dropped — exact under log_softmax.
__global__ __launch_bounds__(256)
void k_soft(const float* __restrict__ Sp, const float* __restrict__ Hs_te,
            float* __restrict__ outp)
{
    __shared__ float red[4], red2[4];
    const int i = blockIdx.x, j = threadIdx.x;
    float s = 0.f;
#pragma unroll
    for (int tc = 0; tc < 16; ++tc)
        s += Sp[((size_t)tc * 256 + i) * 256 + j];
    float v = -(0.5f * s + Hs_te[j]);

    float m = v;
#pragma unroll
    for (int o = 32; o > 0; o >>= 1) m = fmaxf(m, __shfl_xor(m, o));
    if ((j & 63) == 0) red[j >> 6] = m;
    __syncthreads();
    m = fmaxf(fmaxf(red[0], red[1]), fmaxf(red[2], red[3]));

    float p = v - m;
    float t = expf(p);
#pragma unroll
    for (int o = 32; o > 0; o >>= 1) t += __shfl_xor(t, o);
    if ((j & 63) == 0) red2[j >> 6] = t;
    __syncthreads();
    t = red2[0] + red2[1] + red2[2] + red2[3];

    outp[(size_t)i * 256 + j] = p - logf(t);
    if (i == 0) outp[65536 + j] = (float)j;   // classes = arange(256)
}

extern "C" void kernel_launch(void* const* d_in, const int* in_sizes, int n_in,
                              void* d_out, int out_size, void* d_ws, size_t ws_size,
                              hipStream_t stream)
{
    const float* tri = (const float*)d_in[0];   // train_inputs  (256,32,512)
    const float* trt = (const float*)d_in[1];   // train_targets (256,32,1)
    const float* tei = (const float*)d_in[2];   // test_inputs
    const float* tet = (const float*)d_in[3];   // test_targets
    const float* Wfe = (const float*)d_in[4];   // (512,512)
    const float* bfe = (const float*)d_in[5];   // (512,)
    const float* Wlv = (const float*)d_in[6];   // (1026,1026)
    const float* blv = (const float*)d_in[7];   // (1026,)
    float* outp = (float*)d_out;

    float* Z     = (float*)d_ws;                 // 512*1026
    float* E_tr  = Z + (size_t)512 * TDIM;       // 256*1026
    float* R_tr  = E_tr + (size_t)256 * TDIM;
    float* muT   = R_tr + (size_t)256 * TDIM;    // 1026*256 (te, [t][j])
    float* E_teT = muT + (size_t)TDIM * 256;
    float* R_teT = E_teT + (size_t)TDIM * 256;
    float* Hs_te = R_teT + (size_t)TDIM * 256;   // 256
    float* Sp    = Hs_te + 256;                  // 16*256*256

    hipMemsetAsync(Hs_te, 0, 256 * sizeof(float), stream);
    k_fe  <<<dim3(4, 128), 256, 0, stream>>>(tri, tei, Wfe, bfe, Z, muT);
    k_tgt <<<2, 256, 0, stream>>>(trt, tet, Z, muT);
    k_lv  <<<dim3(17, 8), 256, 0, stream>>>(Z, Wlv, blv, E_tr, R_tr, E_teT, R_teT, Hs_te);
    k_pair<<<dim3(32, 16), 256, 0, stream>>>(Z, E_tr, R_tr, muT, E_teT, R_teT, Sp);
    k_soft<<<256, 256, 0, stream>>>(Sp, Hs_te, outp);
}

// Round 2
// 253.785 us; speedup vs baseline: 1.3017x; 1.3017x over previous
//
#include <hip/hip_runtime.h>
#include <math.h>

#define TDIM 1026

typedef __attribute__((ext_vector_type(8))) short bf16x8;
typedef __attribute__((ext_vector_type(4))) float f32x4;

// ---- fp32 -> bf16 RNE helpers ------------------------------------------------
__device__ inline unsigned int pk_bf16(float a, float b) {
    unsigned int ua = __float_as_uint(a), ub = __float_as_uint(b);
    ua = (ua + 0x7FFFu + ((ua >> 16) & 1u)) >> 16;
    ub = (ub + 0x7FFFu + ((ub >> 16) & 1u)) & 0xFFFF0000u;
    return ua | ub;
}
__device__ inline unsigned short f2bf(float a) {
    unsigned int ua = __float_as_uint(a);
    return (unsigned short)((ua + 0x7FFFu + ((ua >> 16) & 1u)) >> 16);
}

// ---- convert A (train rows 0..8191, test rows 8192..16383) to bf16 ----------
__global__ __launch_bounds__(256)
void k_cvta(const float* __restrict__ tri, const float* __restrict__ tei,
            unsigned short* __restrict__ Abf)
{
    size_t g = ((size_t)blockIdx.x * 256 + threadIdx.x) * 8;   // elem idx < 8388608
    const float* src = (g < 4194304) ? (tri + g) : (tei + (g - 4194304));
    float4 v0 = *(const float4*)(src);
    float4 v1 = *(const float4*)(src + 4);
    uint4 o;
    o.x = pk_bf16(v0.x, v0.y); o.y = pk_bf16(v0.z, v0.w);
    o.z = pk_bf16(v1.x, v1.y); o.w = pk_bf16(v1.z, v1.w);
    *(uint4*)(Abf + g) = o;
}

// ---- convert + transpose W_fe (512x512, [k][n]) -> Wt bf16 [n][k] -----------
__global__ __launch_bounds__(256)
void k_cvtw(const float* __restrict__ W, unsigned short* __restrict__ Wt)
{
    __shared__ float T[32][33];
    const int k0 = blockIdx.y * 32, n0 = blockIdx.x * 32;
    const int t = threadIdx.x;
    {
        int ky = t >> 3, nx = (t & 7) * 4;
        float4 v = *(const float4*)(W + (size_t)(k0 + ky) * 512 + n0 + nx);
        T[nx + 0][ky] = v.x; T[nx + 1][ky] = v.y;
        T[nx + 2][ky] = v.z; T[nx + 3][ky] = v.w;
    }
    __syncthreads();
    {
        int ny = t >> 3, kx = (t & 7) * 4;
        ushort4 o;
        o.x = f2bf(T[ny][kx + 0]); o.y = f2bf(T[ny][kx + 1]);
        o.z = f2bf(T[ny][kx + 2]); o.w = f2bf(T[ny][kx + 3]);
        *(ushort4*)(Wt + (size_t)(n0 + ny) * 512 + k0 + kx) = o;
    }
}

// ---- Kernel 1 (fast): bf16 MFMA FE GEMM + bias/relu + per-episode stats -----
// M=16384 (512 eps x 32), N=512, K=512. Tile 128x128, 4 waves 2x2, 16x16x32 MFMA.
// LDS stride 40 elems (80 B): 16B-aligned, breaks 64B power-of-2 bank alias.
__global__ __launch_bounds__(256)
void k_fe_mfma(const unsigned short* __restrict__ Abf,
               const unsigned short* __restrict__ Wt,
               const float* __restrict__ bfe, float* __restrict__ Z,
               float* __restrict__ muT_te)
{
    __shared__ unsigned short As[128 * 40];
    __shared__ unsigned short Bs[128 * 40];
    __shared__ float2 sbuf[4 * 128];

    const int tid  = threadIdx.x;
    const int lane = tid & 63;
    const int wave = tid >> 6;
    const int wr = wave >> 1, wc = wave & 1;
    const int m = lane & 15, quad = lane >> 4;
    const int col0 = blockIdx.x * 128;
    const int row0 = blockIdx.y * 128;

    f32x4 acc[4][4];
#pragma unroll
    for (int i = 0; i < 4; ++i)
#pragma unroll
        for (int j = 0; j < 4; ++j) acc[i][j] = (f32x4){0.f, 0.f, 0.f, 0.f};

    const int srow = tid >> 2;   // + s*64
    const int skc  = tid & 3;

    for (int k0 = 0; k0 < 512; k0 += 32) {
#pragma unroll
        for (int s = 0; s < 2; ++s) {
            int row = srow + s * 64;
            uint4 va = *(const uint4*)(Abf + (size_t)(row0 + row) * 512 + k0 + skc * 8);
            uint4 vb = *(const uint4*)(Wt  + (size_t)(col0 + row) * 512 + k0 + skc * 8);
            *(uint4*)(As + row * 40 + skc * 8) = va;
            *(uint4*)(Bs + row * 40 + skc * 8) = vb;
        }
        __syncthreads();
        bf16x8 af[4], bfr[4];
#pragma unroll
        for (int t2 = 0; t2 < 4; ++t2) {
            af[t2]  = *(const bf16x8*)(As + (wr * 64 + t2 * 16 + m) * 40 + quad * 8);
            bfr[t2] = *(const bf16x8*)(Bs + (wc * 64 + t2 * 16 + m) * 40 + quad * 8);
        }
#pragma unroll
        for (int ti = 0; ti < 4; ++ti)
#pragma unroll
            for (int tj = 0; tj < 4; ++tj)
                acc[ti][tj] = __builtin_amdgcn_mfma_f32_16x16x32_bf16(
                    af[ti], bfr[tj], acc[ti][tj], 0, 0, 0);
        __syncthreads();
    }

    // epilogue: bias + relu, per-episode (32-row) column sums of v, v^2
    // C/D layout: col = lane&15, row = quad*4 + reg. ti pair {2ep,2ep+1} = one episode.
#pragma unroll
    for (int ep = 0; ep < 2; ++ep) {
#pragma unroll
        for (int tj = 0; tj < 4; ++tj) {
            int colL = wc * 64 + tj * 16 + m;
            float b = bfe[col0 + colL];
            float s1 = 0.f, s2 = 0.f;
#pragma unroll
            for (int p = 0; p < 2; ++p) {
                int ti = ep * 2 + p;
#pragma unroll
                for (int r = 0; r < 4; ++r) {
                    float v = fmaxf(acc[ti][tj][r] + b, 0.f);
                    s1 += v; s2 += v * v;
                }
            }
            s1 += __shfl_xor(s1, 16); s1 += __shfl_xor(s1, 32);
            s2 += __shfl_xor(s2, 16); s2 += __shfl_xor(s2, 32);
            if (lane < 16) sbuf[(wr * 2 + ep) * 128 + colL] = make_float2(s1, s2);
        }
    }
    __syncthreads();
    for (int idx = tid; idx < 512; idx += 256) {
        int ep = idx >> 7, cl = idx & 127;
        float2 pr = sbuf[ep * 128 + cl];
        float mean = pr.x * (1.f / 32.f);
        float var  = (pr.y - 32.f * mean * mean) * (1.f / 31.f);   // ddof=1
        float sd   = sqrtf(fmaxf(var, 0.f));
        int e = blockIdx.y * 4 + ep;
        int f = col0 + cl;
        Z[(size_t)e * TDIM + 1 + f]   = mean;
        Z[(size_t)e * TDIM + 514 + f] = sd;
        if (e >= 256) {
            int j2 = e - 256;
            muT_te[(size_t)(1 + f) * 256 + j2]   = mean;
            muT_te[(size_t)(514 + f) * 256 + j2] = sd;
        }
    }
}

// ---- Kernel 1 (fallback, fp32 — used only if ws too small) -------------------
__global__ __launch_bounds__(256)
void k_fe_f32(const float* __restrict__ Atr, const float* __restrict__ Ate,
              const float* __restrict__ Wfe, const float* __restrict__ bfe,
              float* __restrict__ Z, float* __restrict__ muT_te)
{
    __shared__ float lds[4224];
    float* Ast = lds;
    float* Bs  = lds + 2112;

    const int tid = threadIdx.x;
    const int tx = tid & 15;
    const int ty = tid >> 4;
    const int col0 = blockIdx.x * 128;
    const int row0 = blockIdx.y * 128;
    const float* A = (row0 < 8192) ? Atr : Ate;
    const int ar0 = (row0 < 8192) ? row0 : (row0 - 8192);

    float acc[8][8];
#pragma unroll
    for (int i = 0; i < 8; ++i)
#pragma unroll
        for (int j = 0; j < 8; ++j) acc[i][j] = 0.f;

    for (int k0 = 0; k0 < 512; k0 += 16) {
#pragma unroll
        for (int s = 0; s < 2; ++s) {
            int u = tid + s * 256;
            int row = u >> 2, q = u & 3;
            float4 v = *(const float4*)(A + (size_t)(ar0 + row) * 512 + k0 + q * 4);
            Ast[(q * 4 + 0) * 132 + row] = v.x;
            Ast[(q * 4 + 1) * 132 + row] = v.y;
            Ast[(q * 4 + 2) * 132 + row] = v.z;
            Ast[(q * 4 + 3) * 132 + row] = v.w;
        }
#pragma unroll
        for (int s = 0; s < 2; ++s) {
            int u = tid + s * 256;
            int kk = u >> 5, c8 = u & 31;
            float4 v = *(const float4*)(Wfe + (size_t)(k0 + kk) * 512 + col0 + c8 * 4);
            *(float4*)(Bs + kk * 132 + c8 * 4) = v;
        }
        __syncthreads();
#pragma unroll
        for (int kk = 0; kk < 16; ++kk) {
            float4 a0 = *(const float4*)(Ast + kk * 132 + ty * 8);
            float4 a1 = *(const float4*)(Ast + kk * 132 + ty * 8 + 4);
            float4 b0 = *(const float4*)(Bs + kk * 132 + tx * 4);
            float4 b1 = *(const float4*)(Bs + kk * 132 + 64 + tx * 4);
            float av[8] = {a0.x, a0.y, a0.z, a0.w, a1.x, a1.y, a1.z, a1.w};
            float bv[8] = {b0.x, b0.y, b0.z, b0.w, b1.x, b1.y, b1.z, b1.w};
#pragma unroll
            for (int i = 0; i < 8; ++i)
#pragma unroll
                for (int j = 0; j < 8; ++j)
                    acc[i][j] = fmaf(av[i], bv[j], acc[i][j]);
        }
        __syncthreads();
    }

    float2* sbuf = (float2*)lds;
#pragma unroll
    for (int j = 0; j < 8; ++j) {
        int cl = (j < 4) ? (tx * 4 + j) : (64 + tx * 4 + (j - 4));
        float b = bfe[col0 + cl];
        float s1 = 0.f, s2 = 0.f;
#pragma unroll
        for (int i = 0; i < 8; ++i) {
            float v = acc[i][j] + b;
            v = fmaxf(v, 0.f);
            s1 += v; s2 += v * v;
        }
        sbuf[ty * 128 + cl] = make_float2(s1, s2);
    }
    __syncthreads();
    for (int idx = tid; idx < 512; idx += 256) {
        int ep = idx >> 7, cl = idx & 127;
        float S1 = 0.f, S2 = 0.f;
#pragma unroll
        for (int q = 0; q < 4; ++q) {
            float2 p = sbuf[(ep * 4 + q) * 128 + cl];
            S1 += p.x; S2 += p.y;
        }
        float mean = S1 * (1.f / 32.f);
        float var  = (S2 - 32.f * mean * mean) * (1.f / 31.f);
        float sd   = sqrtf(fmaxf(var, 0.f));
        int e = (row0 >> 5) + ep;
        int f = col0 + cl;
        Z[(size_t)e * TDIM + 1 + f]   = mean;
        Z[(size_t)e * TDIM + 514 + f] = sd;
        if (e >= 256) {
            int j2 = e - 256;
            muT_te[(size_t)(1 + f) * 256 + j2]   = mean;
            muT_te[(size_t)(514 + f) * 256 + j2] = sd;
        }
    }
}

// ---------------- Kernel 2: targets column stats (x col 0) ----------------
__global__ __launch_bounds__(256)
void k_tgt(const float* __restrict__ Ttr, const float* __restrict__ Tte,
           float* __restrict__ Z, float* __restrict__ muT_te)
{
    int e = blockIdx.x * 256 + threadIdx.x;
    if (e >= 512) return;
    const float* p = (e < 256) ? (Ttr + (size_t)e * 32) : (Tte + (size_t)(e - 256) * 32);
    float S1 = 0.f, S2 = 0.f;
#pragma unroll
    for (int n = 0; n < 32; ++n) { float v = p[n]; S1 += v; S2 += v * v; }
    float mean = S1 * (1.f / 32.f);
    float var  = (S2 - 32.f * mean * mean) * (1.f / 31.f);
    float sd   = sqrtf(fmaxf(var, 0.f));
    Z[(size_t)e * TDIM + 0]   = mean;
    Z[(size_t)e * TDIM + 513] = sd;
    if (e >= 256) {
        muT_te[(size_t)0 * 256 + (e - 256)]   = mean;
        muT_te[(size_t)513 * 256 + (e - 256)] = sd;
    }
}

// ---------------- Kernel 3: LV GEMM (Z @ W_lv + b) -> clip/exp/H --------------
__global__ __launch_bounds__(256)
void k_lv(const float* __restrict__ Z, const float* __restrict__ Wlv,
          const float* __restrict__ blv,
          float* __restrict__ E_tr, float* __restrict__ R_tr,
          float* __restrict__ E_teT, float* __restrict__ R_teT,
          float* __restrict__ Hs_te)
{
    __shared__ float Ast[16 * 68];
    __shared__ float Bs[16 * 68];
    const int tid = threadIdx.x;
    const int tx = tid & 15;
    const int ty = tid >> 4;
    const int col0 = blockIdx.x * 64;
    const int row0 = blockIdx.y * 64;

    float acc[4][4];
#pragma unroll
    for (int i = 0; i < 4; ++i)
#pragma unroll
        for (int j = 0; j < 4; ++j) acc[i][j] = 0.f;

    for (int k0 = 0; k0 < TDIM; k0 += 16) {
        {
            int row = tid >> 2, kp = tid & 3;
            const float* src = Z + (size_t)(row0 + row) * TDIM + k0 + kp * 4;
            float x0 = 0.f, x1 = 0.f, x2 = 0.f, x3 = 0.f;
            if (k0 + kp * 4 + 1 < TDIM) { float2 v = *(const float2*)(src);     x0 = v.x; x1 = v.y; }
            if (k0 + kp * 4 + 3 < TDIM) { float2 v = *(const float2*)(src + 2); x2 = v.x; x3 = v.y; }
            Ast[(kp * 4 + 0) * 68 + row] = x0;
            Ast[(kp * 4 + 1) * 68 + row] = x1;
            Ast[(kp * 4 + 2) * 68 + row] = x2;
            Ast[(kp * 4 + 3) * 68 + row] = x3;
        }
        {
            int kk = tid >> 4, cg = tid & 15;
#pragma unroll
            for (int c = 0; c < 4; ++c) {
                int col = col0 + cg * 4 + c;
                float v = 0.f;
                if (k0 + kk < TDIM && col < TDIM)
                    v = Wlv[(size_t)(k0 + kk) * TDIM + col];
                Bs[kk * 68 + cg * 4 + c] = v;
            }
        }
        __syncthreads();
#pragma unroll
        for (int kk = 0; kk < 16; ++kk) {
            float4 a = *(const float4*)(Ast + kk * 68 + ty * 4);
            float4 b = *(const float4*)(Bs + kk * 68 + tx * 4);
            float av[4] = {a.x, a.y, a.z, a.w};
            float bv[4] = {b.x, b.y, b.z, b.w};
#pragma unroll
            for (int i = 0; i < 4; ++i)
#pragma unroll
                for (int j = 0; j < 4; ++j)
                    acc[i][j] = fmaf(av[i], bv[j], acc[i][j]);
        }
        __syncthreads();
    }

    float hpart[4] = {0.f, 0.f, 0.f, 0.f};
#pragma unroll
    for (int i = 0; i < 4; ++i) {
        int r = row0 + ty * 4 + i;
#pragma unroll
        for (int j = 0; j < 4; ++j) {
            int c = col0 + tx * 4 + j;
            if (c < TDIM) {
                float lv = acc[i][j] + blv[c];
                lv = fminf(fmaxf(lv, -9.f), -2.f);
                float E = expf(lv);
                float R = expf(-lv);
                if (r < 256) {
                    E_tr[(size_t)r * TDIM + c] = E;
                    R_tr[(size_t)r * TDIM + c] = R;
                } else {
                    E_teT[(size_t)c * 256 + (r - 256)] = E;
                    R_teT[(size_t)c * 256 + (r - 256)] = R;
                    hpart[i] += lv;
                }
            }
        }
    }
    if (row0 >= 256) {
        __syncthreads();
        float* hbuf = Ast;
#pragma unroll
        for (int i = 0; i < 4; ++i) hbuf[(ty * 4 + i) * 16 + tx] = hpart[i];
        __syncthreads();
        if (tid < 64) {
            float s = 0.f;
#pragma unroll
            for (int x = 0; x < 16; ++x) s += hbuf[tid * 16 + x];
            atomicAdd(Hs_te + (row0 - 256 + tid), s);
        }
    }
}

// ---------------- Kernel 4: pairwise partial sums -----------------------------
#define TCH 65
__global__ __launch_bounds__(256)
void k_pair(const float* __restrict__ Z, const float* __restrict__ E_tr,
            const float* __restrict__ R_tr, const float* __restrict__ muT_te,
            const float* __restrict__ E_teT, const float* __restrict__ R_teT,
            float* __restrict__ Sp)
{
    __shared__ float Lm[8 * 68], Le[8 * 68], Lr[8 * 68];
    const int tid = threadIdx.x;
    const int i0 = blockIdx.x * 8;
    const int t0 = blockIdx.y * TCH;
    const int tlen = min(TCH, TDIM - t0);

    if (tid < tlen) {
#pragma unroll
        for (int r = 0; r < 8; ++r) {
            size_t off = (size_t)(i0 + r) * TDIM + t0 + tid;
            Lm[r * 68 + tid] = Z[off];
            Le[r * 68 + tid] = E_tr[off];
            Lr[r * 68 + tid] = R_tr[off];
        }
    }
    __syncthreads();

    float S[8];
#pragma unroll
    for (int r = 0; r < 8; ++r) S[r] = 0.f;
    const int j = tid;
    for (int tt = 0; tt < tlen; ++tt) {
        size_t o = (size_t)(t0 + tt) * 256 + j;
        float m2 = muT_te[o], e2 = E_teT[o], r2 = R_teT[o];
#pragma unroll
        for (int r = 0; r < 8; ++r) {
            float m1 = Lm[r * 68 + tt];
            float e1 = Le[r * 68 + tt];
            float r1 = Lr[r * 68 + tt];
            float d = m1 - m2;
            S[r] += e1 * r2 + e2 * r1 + d * d * (r1 + r2);
        }
    }
#pragma unroll
    for (int r = 0; r < 8; ++r)
        Sp[((size_t)blockIdx.y * 256 + i0 + r) * 256 + j] = S[r];
}

// ---------------- Kernel 5: row log_softmax + classes -------------------------
__global__ __launch_bounds__(256)
void k_soft(const float* __restrict__ Sp, const float* __restrict__ Hs_te,
            float* __restrict__ outp)
{
    __shared__ float red[4], red2[4];
    const int i = blockIdx.x, j = threadIdx.x;
    float s = 0.f;
#pragma unroll
    for (int tc = 0; tc < 16; ++tc)
        s += Sp[((size_t)tc * 256 + i) * 256 + j];
    float v = -(0.5f * s + Hs_te[j]);

    float m = v;
#pragma unroll
    for (int o = 32; o > 0; o >>= 1) m = fmaxf(m, __shfl_xor(m, o));
    if ((j & 63) == 0) red[j >> 6] = m;
    __syncthreads();
    m = fmaxf(fmaxf(red[0], red[1]), fmaxf(red[2], red[3]));

    float p = v - m;
    float t = expf(p);
#pragma unroll
    for (int o = 32; o > 0; o >>= 1) t += __shfl_xor(t, o);
    if ((j & 63) == 0) red2[j >> 6] = t;
    __syncthreads();
    t = red2[0] + red2[1] + red2[2] + red2[3];

    outp[(size_t)i * 256 + j] = p - logf(t);
    if (i == 0) outp[65536 + j] = (float)j;
}

extern "C" void kernel_launch(void* const* d_in, const int* in_sizes, int n_in,
                              void* d_out, int out_size, void* d_ws, size_t ws_size,
                              hipStream_t stream)
{
    const float* tri = (const float*)d_in[0];
    const float* trt = (const float*)d_in[1];
    const float* tei = (const float*)d_in[2];
    const float* tet = (const float*)d_in[3];
    const float* Wfe = (const float*)d_in[4];
    const float* bfe = (const float*)d_in[5];
    const float* Wlv = (const float*)d_in[6];
    const float* blv = (const float*)d_in[7];
    float* outp = (float*)d_out;

    float* Z     = (float*)d_ws;                 // 512*1026
    float* E_tr  = Z + (size_t)512 * TDIM;
    float* R_tr  = E_tr + (size_t)256 * TDIM;
    float* muT   = R_tr + (size_t)256 * TDIM;
    float* E_teT = muT + (size_t)TDIM * 256;
    float* R_teT = E_teT + (size_t)TDIM * 256;
    float* Hs_te = R_teT + (size_t)TDIM * 256;   // 256
    float* Sp    = Hs_te + 256;                  // 16*256*256
    float* endf  = Sp + (size_t)16 * 256 * 256;  // = ws + 2887424 floats (11549696 B, 16B-aligned)
    unsigned short* Abf = (unsigned short*)endf;          // 16384*512 bf16 = 16 MB
    unsigned short* Wt  = Abf + (size_t)16384 * 512;      // 512*512 bf16 [n][k]

    const size_t need = 11549696ull + 16777216ull + 524288ull;
    const bool fast = (ws_size >= need);

    hipMemsetAsync(Hs_te, 0, 256 * sizeof(float), stream);
    if (fast) {
        k_cvta<<<4096, 256, 0, stream>>>(tri, tei, Abf);
        k_cvtw<<<dim3(16, 16), 256, 0, stream>>>(Wfe, Wt);
        k_fe_mfma<<<dim3(4, 128), 256, 0, stream>>>(Abf, Wt, bfe, Z, muT);
    } else {
        k_fe_f32<<<dim3(4, 128), 256, 0, stream>>>(tri, tei, Wfe, bfe, Z, muT);
    }
    k_tgt <<<2, 256, 0, stream>>>(trt, tet, Z, muT);
    k_lv  <<<dim3(17, 8), 256, 0, stream>>>(Z, Wlv, blv, E_tr, R_tr, E_teT, R_teT, Hs_te);
    k_pair<<<dim3(32, 16), 256, 0, stream>>>(Z, E_tr, R_tr, muT, E_teT, R_teT, Sp);
    k_soft<<<256, 256, 0, stream>>>(Sp, Hs_te, outp);
}

// Round 3
// 203.440 us; speedup vs baseline: 1.6238x; 1.2475x over previous
//
#include <hip/hip_runtime.h>
#include <math.h>

#define TDIM 1026
#define KP 1056          // K padded for LV GEMM (33 * 32)
#define NP 1152          // N padded for LV GEMM (9 * 128)

typedef __attribute__((ext_vector_type(8))) short bf16x8;
typedef __attribute__((ext_vector_type(4))) float f32x4;

// ---- fp32 -> bf16 RNE helpers ------------------------------------------------
__device__ inline unsigned int pk_bf16(float a, float b) {
    unsigned int ua = __float_as_uint(a), ub = __float_as_uint(b);
    ua = (ua + 0x7FFFu + ((ua >> 16) & 1u)) >> 16;
    ub = (ub + 0x7FFFu + ((ub >> 16) & 1u)) & 0xFFFF0000u;
    return ua | ub;
}
__device__ inline unsigned short f2bf(float a) {
    unsigned int ua = __float_as_uint(a);
    return (unsigned short)((ua + 0x7FFFu + ((ua >> 16) & 1u)) >> 16);
}

// ---- convert A (train rows 0..8191, test rows 8192..16383) to bf16 ----------
__global__ __launch_bounds__(256)
void k_cvta(const float* __restrict__ tri, const float* __restrict__ tei,
            unsigned short* __restrict__ Abf)
{
    size_t g = ((size_t)blockIdx.x * 256 + threadIdx.x) * 8;
    const float* src = (g < 4194304) ? (tri + g) : (tei + (g - 4194304));
    float4 v0 = *(const float4*)(src);
    float4 v1 = *(const float4*)(src + 4);
    uint4 o;
    o.x = pk_bf16(v0.x, v0.y); o.y = pk_bf16(v0.z, v0.w);
    o.z = pk_bf16(v1.x, v1.y); o.w = pk_bf16(v1.z, v1.w);
    *(uint4*)(Abf + g) = o;
}

// ---- convert + transpose W_fe (512x512, [k][n]) -> Wt bf16 [n][k] -----------
__global__ __launch_bounds__(256)
void k_cvtw(const float* __restrict__ W, unsigned short* __restrict__ Wt)
{
    __shared__ float T[32][33];
    const int k0 = blockIdx.y * 32, n0 = blockIdx.x * 32;
    const int t = threadIdx.x;
    {
        int ky = t >> 3, nx = (t & 7) * 4;
        float4 v = *(const float4*)(W + (size_t)(k0 + ky) * 512 + n0 + nx);
        T[nx + 0][ky] = v.x; T[nx + 1][ky] = v.y;
        T[nx + 2][ky] = v.z; T[nx + 3][ky] = v.w;
    }
    __syncthreads();
    {
        int ny = t >> 3, kx = (t & 7) * 4;
        ushort4 o;
        o.x = f2bf(T[ny][kx + 0]); o.y = f2bf(T[ny][kx + 1]);
        o.z = f2bf(T[ny][kx + 2]); o.w = f2bf(T[ny][kx + 3]);
        *(ushort4*)(Wt + (size_t)(n0 + ny) * 512 + k0 + kx) = o;
    }
}

// ---- convert + transpose W_lv (1026x1026 [k][n]) -> Wlt bf16 [n][KP], padded -
__global__ __launch_bounds__(256)
void k_cvtwlv(const float* __restrict__ W, unsigned short* __restrict__ Wlt)
{
    __shared__ float T[32][33];
    const int n0 = blockIdx.x * 32, k0 = blockIdx.y * 32;
    const int t = threadIdx.x;
    {
        int ky = t >> 3, nx = (t & 7) * 4;
#pragma unroll
        for (int i = 0; i < 4; ++i) {
            float v = 0.f;
            if (k0 + ky < TDIM && n0 + nx + i < TDIM)
                v = W[(size_t)(k0 + ky) * TDIM + n0 + nx + i];
            T[nx + i][ky] = v;
        }
    }
    __syncthreads();
    {
        int ny = t >> 3, kx = (t & 7) * 4;
        ushort4 o;
        o.x = f2bf(T[ny][kx + 0]); o.y = f2bf(T[ny][kx + 1]);
        o.z = f2bf(T[ny][kx + 2]); o.w = f2bf(T[ny][kx + 3]);
        *(ushort4*)(Wlt + (size_t)(n0 + ny) * KP + k0 + kx) = o;
    }
}

// ---- Kernel 1 (fast): bf16 MFMA FE GEMM + bias/relu + per-episode stats -----
__global__ __launch_bounds__(256)
void k_fe_mfma(const unsigned short* __restrict__ Abf,
               const unsigned short* __restrict__ Wt,
               const float* __restrict__ bfe, float* __restrict__ Z,
               unsigned short* __restrict__ Zb, float* __restrict__ muT_te)
{
    __shared__ unsigned short As[128 * 40];
    __shared__ unsigned short Bs[128 * 40];
    __shared__ float2 sbuf[4 * 128];

    const int tid  = threadIdx.x;
    const int lane = tid & 63;
    const int wave = tid >> 6;
    const int wr = wave >> 1, wc = wave & 1;
    const int m = lane & 15, quad = lane >> 4;
    const int col0 = blockIdx.x * 128;
    const int row0 = blockIdx.y * 128;

    f32x4 acc[4][4];
#pragma unroll
    for (int i = 0; i < 4; ++i)
#pragma unroll
        for (int j = 0; j < 4; ++j) acc[i][j] = (f32x4){0.f, 0.f, 0.f, 0.f};

    const int srow = tid >> 2;
    const int skc  = tid & 3;

    for (int k0 = 0; k0 < 512; k0 += 32) {
#pragma unroll
        for (int s = 0; s < 2; ++s) {
            int row = srow + s * 64;
            uint4 va = *(const uint4*)(Abf + (size_t)(row0 + row) * 512 + k0 + skc * 8);
            uint4 vb = *(const uint4*)(Wt  + (size_t)(col0 + row) * 512 + k0 + skc * 8);
            *(uint4*)(As + row * 40 + skc * 8) = va;
            *(uint4*)(Bs + row * 40 + skc * 8) = vb;
        }
        __syncthreads();
        bf16x8 af[4], bfr[4];
#pragma unroll
        for (int t2 = 0; t2 < 4; ++t2) {
            af[t2]  = *(const bf16x8*)(As + (wr * 64 + t2 * 16 + m) * 40 + quad * 8);
            bfr[t2] = *(const bf16x8*)(Bs + (wc * 64 + t2 * 16 + m) * 40 + quad * 8);
        }
#pragma unroll
        for (int ti = 0; ti < 4; ++ti)
#pragma unroll
            for (int tj = 0; tj < 4; ++tj)
                acc[ti][tj] = __builtin_amdgcn_mfma_f32_16x16x32_bf16(
                    af[ti], bfr[tj], acc[ti][tj], 0, 0, 0);
        __syncthreads();
    }

#pragma unroll
    for (int ep = 0; ep < 2; ++ep) {
#pragma unroll
        for (int tj = 0; tj < 4; ++tj) {
            int colL = wc * 64 + tj * 16 + m;
            float b = bfe[col0 + colL];
            float s1 = 0.f, s2 = 0.f;
#pragma unroll
            for (int p = 0; p < 2; ++p) {
                int ti = ep * 2 + p;
#pragma unroll
                for (int r = 0; r < 4; ++r) {
                    float v = fmaxf(acc[ti][tj][r] + b, 0.f);
                    s1 += v; s2 += v * v;
                }
            }
            s1 += __shfl_xor(s1, 16); s1 += __shfl_xor(s1, 32);
            s2 += __shfl_xor(s2, 16); s2 += __shfl_xor(s2, 32);
            if (lane < 16) sbuf[(wr * 2 + ep) * 128 + colL] = make_float2(s1, s2);
        }
    }
    __syncthreads();
    for (int idx = tid; idx < 512; idx += 256) {
        int ep = idx >> 7, cl = idx & 127;
        float2 pr = sbuf[ep * 128 + cl];
        float mean = pr.x * (1.f / 32.f);
        float var  = (pr.y - 32.f * mean * mean) * (1.f / 31.f);   // ddof=1
        float sd   = sqrtf(fmaxf(var, 0.f));
        int e = blockIdx.y * 4 + ep;
        int f = col0 + cl;
        Z[(size_t)e * TDIM + 1 + f]   = mean;
        Z[(size_t)e * TDIM + 514 + f] = sd;
        Zb[(size_t)e * KP + 1 + f]    = f2bf(mean);
        Zb[(size_t)e * KP + 514 + f]  = f2bf(sd);
        if (e >= 256) {
            int j2 = e - 256;
            muT_te[(size_t)(1 + f) * 256 + j2]   = mean;
            muT_te[(size_t)(514 + f) * 256 + j2] = sd;
        }
    }
}

// ---------------- Kernel 2: targets column stats + Zb pad zeroing -------------
__global__ __launch_bounds__(256)
void k_tgt(const float* __restrict__ Ttr, const float* __restrict__ Tte,
           float* __restrict__ Z, unsigned short* __restrict__ Zb,
           float* __restrict__ muT_te)
{
    int e = blockIdx.x * 256 + threadIdx.x;
    if (e >= 512) return;
    const float* p = (e < 256) ? (Ttr + (size_t)e * 32) : (Tte + (size_t)(e - 256) * 32);
    float S1 = 0.f, S2 = 0.f;
#pragma unroll
    for (int n = 0; n < 32; ++n) { float v = p[n]; S1 += v; S2 += v * v; }
    float mean = S1 * (1.f / 32.f);
    float var  = (S2 - 32.f * mean * mean) * (1.f / 31.f);
    float sd   = sqrtf(fmaxf(var, 0.f));
    Z[(size_t)e * TDIM + 0]   = mean;
    Z[(size_t)e * TDIM + 513] = sd;
    Zb[(size_t)e * KP + 0]    = f2bf(mean);
    Zb[(size_t)e * KP + 513]  = f2bf(sd);
#pragma unroll
    for (int c = TDIM; c < KP; ++c) Zb[(size_t)e * KP + c] = 0;   // K pad (ws re-poisoned)
    if (e >= 256) {
        muT_te[(size_t)0 * 256 + (e - 256)]   = mean;
        muT_te[(size_t)513 * 256 + (e - 256)] = sd;
    }
}

// ---- Kernel 3 (fast): bf16 MFMA LV GEMM + clip/exp/H -------------------------
// M=512 (rows=episodes), N=1152 (pad of 1026), K=1056 (pad of 1026). Tile 128x128.
__global__ __launch_bounds__(256)
void k_lv_mfma(const unsigned short* __restrict__ Zb,
               const unsigned short* __restrict__ Wlt,
               const float* __restrict__ blv,
               float* __restrict__ E_tr, float* __restrict__ R_tr,
               float* __restrict__ E_teT, float* __restrict__ R_teT,
               float* __restrict__ Hs_te)
{
    __shared__ unsigned short As[128 * 40];
    __shared__ unsigned short Bs[128 * 40];

    const int tid  = threadIdx.x;
    const int lane = tid & 63;
    const int wave = tid >> 6;
    const int wr = wave >> 1, wc = wave & 1;
    const int m = lane & 15, quad = lane >> 4;
    const int col0 = blockIdx.x * 128;
    const int row0 = blockIdx.y * 128;
    const bool is_te = (row0 >= 256);

    f32x4 acc[4][4];
#pragma unroll
    for (int i = 0; i < 4; ++i)
#pragma unroll
        for (int j = 0; j < 4; ++j) acc[i][j] = (f32x4){0.f, 0.f, 0.f, 0.f};

    const int srow = tid >> 2;
    const int skc  = tid & 3;

    for (int k0 = 0; k0 < KP; k0 += 32) {
#pragma unroll
        for (int s = 0; s < 2; ++s) {
            int row = srow + s * 64;
            uint4 va = *(const uint4*)(Zb  + (size_t)(row0 + row) * KP + k0 + skc * 8);
            uint4 vb = *(const uint4*)(Wlt + (size_t)(col0 + row) * KP + k0 + skc * 8);
            *(uint4*)(As + row * 40 + skc * 8) = va;
            *(uint4*)(Bs + row * 40 + skc * 8) = vb;
        }
        __syncthreads();
        bf16x8 af[4], bfr[4];
#pragma unroll
        for (int t2 = 0; t2 < 4; ++t2) {
            af[t2]  = *(const bf16x8*)(As + (wr * 64 + t2 * 16 + m) * 40 + quad * 8);
            bfr[t2] = *(const bf16x8*)(Bs + (wc * 64 + t2 * 16 + m) * 40 + quad * 8);
        }
#pragma unroll
        for (int ti = 0; ti < 4; ++ti)
#pragma unroll
            for (int tj = 0; tj < 4; ++tj)
                acc[ti][tj] = __builtin_amdgcn_mfma_f32_16x16x32_bf16(
                    af[ti], bfr[tj], acc[ti][tj], 0, 0, 0);
        __syncthreads();
    }

    // epilogue: C/D layout col=lane&15 (within tj frag), row=quad*4+reg (within ti frag)
#pragma unroll
    for (int ti = 0; ti < 4; ++ti) {
        float h[4] = {0.f, 0.f, 0.f, 0.f};
#pragma unroll
        for (int tj = 0; tj < 4; ++tj) {
            int c = col0 + wc * 64 + tj * 16 + m;
            bool cok = (c < TDIM);
            float b = cok ? blv[c] : 0.f;
#pragma unroll
            for (int r = 0; r < 4; ++r) {
                int rg = row0 + wr * 64 + ti * 16 + quad * 4 + r;
                float lv = acc[ti][tj][r] + b;
                lv = fminf(fmaxf(lv, -9.f), -2.f);
                if (cok) {
                    float E = expf(lv);
                    float R = expf(-lv);
                    if (rg < 256) {
                        E_tr[(size_t)rg * TDIM + c] = E;
                        R_tr[(size_t)rg * TDIM + c] = R;
                    } else {
                        E_teT[(size_t)c * 256 + (rg - 256)] = E;
                        R_teT[(size_t)c * 256 + (rg - 256)] = R;
                        h[r] += lv;
                    }
                }
            }
        }
        if (is_te) {
#pragma unroll
            for (int r = 0; r < 4; ++r) {
                float v = h[r];
                v += __shfl_xor(v, 1); v += __shfl_xor(v, 2);
                v += __shfl_xor(v, 4); v += __shfl_xor(v, 8);
                if (m == 0)
                    atomicAdd(Hs_te + (row0 + wr * 64 + ti * 16 + quad * 4 + r - 256), v);
            }
        }
    }
}

// ---- Kernel 3 (fallback, fp32) ----------------------------------------------
__global__ __launch_bounds__(256)
void k_lv(const float* __restrict__ Z, const float* __restrict__ Wlv,
          const float* __restrict__ blv,
          float* __restrict__ E_tr, float* __restrict__ R_tr,
          float* __restrict__ E_teT, float* __restrict__ R_teT,
          float* __restrict__ Hs_te)
{
    __shared__ float Ast[16 * 68];
    __shared__ float Bs[16 * 68];
    const int tid = threadIdx.x;
    const int tx = tid & 15;
    const int ty = tid >> 4;
    const int col0 = blockIdx.x * 64;
    const int row0 = blockIdx.y * 64;

    float acc[4][4];
#pragma unroll
    for (int i = 0; i < 4; ++i)
#pragma unroll
        for (int j = 0; j < 4; ++j) acc[i][j] = 0.f;

    for (int k0 = 0; k0 < TDIM; k0 += 16) {
        {
            int row = tid >> 2, kp = tid & 3;
            const float* src = Z + (size_t)(row0 + row) * TDIM + k0 + kp * 4;
            float x0 = 0.f, x1 = 0.f, x2 = 0.f, x3 = 0.f;
            if (k0 + kp * 4 + 1 < TDIM) { float2 v = *(const float2*)(src);     x0 = v.x; x1 = v.y; }
            if (k0 + kp * 4 + 3 < TDIM) { float2 v = *(const float2*)(src + 2); x2 = v.x; x3 = v.y; }
            Ast[(kp * 4 + 0) * 68 + row] = x0;
            Ast[(kp * 4 + 1) * 68 + row] = x1;
            Ast[(kp * 4 + 2) * 68 + row] = x2;
            Ast[(kp * 4 + 3) * 68 + row] = x3;
        }
        {
            int kk = tid >> 4, cg = tid & 15;
#pragma unroll
            for (int c = 0; c < 4; ++c) {
                int col = col0 + cg * 4 + c;
                float v = 0.f;
                if (k0 + kk < TDIM && col < TDIM)
                    v = Wlv[(size_t)(k0 + kk) * TDIM + col];
                Bs[kk * 68 + cg * 4 + c] = v;
            }
        }
        __syncthreads();
#pragma unroll
        for (int kk = 0; kk < 16; ++kk) {
            float4 a = *(const float4*)(Ast + kk * 68 + ty * 4);
            float4 b = *(const float4*)(Bs + kk * 68 + tx * 4);
            float av[4] = {a.x, a.y, a.z, a.w};
            float bv[4] = {b.x, b.y, b.z, b.w};
#pragma unroll
            for (int i = 0; i < 4; ++i)
#pragma unroll
                for (int j = 0; j < 4; ++j)
                    acc[i][j] = fmaf(av[i], bv[j], acc[i][j]);
        }
        __syncthreads();
    }

    float hpart[4] = {0.f, 0.f, 0.f, 0.f};
#pragma unroll
    for (int i = 0; i < 4; ++i) {
        int r = row0 + ty * 4 + i;
#pragma unroll
        for (int j = 0; j < 4; ++j) {
            int c = col0 + tx * 4 + j;
            if (c < TDIM) {
                float lv = acc[i][j] + blv[c];
                lv = fminf(fmaxf(lv, -9.f), -2.f);
                float E = expf(lv);
                float R = expf(-lv);
                if (r < 256) {
                    E_tr[(size_t)r * TDIM + c] = E;
                    R_tr[(size_t)r * TDIM + c] = R;
                } else {
                    E_teT[(size_t)c * 256 + (r - 256)] = E;
                    R_teT[(size_t)c * 256 + (r - 256)] = R;
                    hpart[i] += lv;
                }
            }
        }
    }
    if (row0 >= 256) {
        __syncthreads();
        float* hbuf = Ast;
#pragma unroll
        for (int i = 0; i < 4; ++i) hbuf[(ty * 4 + i) * 16 + tx] = hpart[i];
        __syncthreads();
        if (tid < 64) {
            float s = 0.f;
#pragma unroll
            for (int x = 0; x < 16; ++x) s += hbuf[tid * 16 + x];
            atomicAdd(Hs_te + (row0 - 256 + tid), s);
        }
    }
}

// ---- Kernel 1 (fallback, fp32) ----------------------------------------------
__global__ __launch_bounds__(256)
void k_fe_f32(const float* __restrict__ Atr, const float* __restrict__ Ate,
              const float* __restrict__ Wfe, const float* __restrict__ bfe,
              float* __restrict__ Z, float* __restrict__ muT_te)
{
    __shared__ float lds[4224];
    float* Ast = lds;
    float* Bs  = lds + 2112;

    const int tid = threadIdx.x;
    const int tx = tid & 15;
    const int ty = tid >> 4;
    const int col0 = blockIdx.x * 128;
    const int row0 = blockIdx.y * 128;
    const float* A = (row0 < 8192) ? Atr : Ate;
    const int ar0 = (row0 < 8192) ? row0 : (row0 - 8192);

    float acc[8][8];
#pragma unroll
    for (int i = 0; i < 8; ++i)
#pragma unroll
        for (int j = 0; j < 8; ++j) acc[i][j] = 0.f;

    for (int k0 = 0; k0 < 512; k0 += 16) {
#pragma unroll
        for (int s = 0; s < 2; ++s) {
            int u = tid + s * 256;
            int row = u >> 2, q = u & 3;
            float4 v = *(const float4*)(A + (size_t)(ar0 + row) * 512 + k0 + q * 4);
            Ast[(q * 4 + 0) * 132 + row] = v.x;
            Ast[(q * 4 + 1) * 132 + row] = v.y;
            Ast[(q * 4 + 2) * 132 + row] = v.z;
            Ast[(q * 4 + 3) * 132 + row] = v.w;
        }
#pragma unroll
        for (int s = 0; s < 2; ++s) {
            int u = tid + s * 256;
            int kk = u >> 5, c8 = u & 31;
            float4 v = *(const float4*)(Wfe + (size_t)(k0 + kk) * 512 + col0 + c8 * 4);
            *(float4*)(Bs + kk * 132 + c8 * 4) = v;
        }
        __syncthreads();
#pragma unroll
        for (int kk = 0; kk < 16; ++kk) {
            float4 a0 = *(const float4*)(Ast + kk * 132 + ty * 8);
            float4 a1 = *(const float4*)(Ast + kk * 132 + ty * 8 + 4);
            float4 b0 = *(const float4*)(Bs + kk * 132 + tx * 4);
            float4 b1 = *(const float4*)(Bs + kk * 132 + 64 + tx * 4);
            float av[8] = {a0.x, a0.y, a0.z, a0.w, a1.x, a1.y, a1.z, a1.w};
            float bv[8] = {b0.x, b0.y, b0.z, b0.w, b1.x, b1.y, b1.z, b1.w};
#pragma unroll
            for (int i = 0; i < 8; ++i)
#pragma unroll
                for (int j = 0; j < 8; ++j)
                    acc[i][j] = fmaf(av[i], bv[j], acc[i][j]);
        }
        __syncthreads();
    }

    float2* sbuf = (float2*)lds;
#pragma unroll
    for (int j = 0; j < 8; ++j) {
        int cl = (j < 4) ? (tx * 4 + j) : (64 + tx * 4 + (j - 4));
        float b = bfe[col0 + cl];
        float s1 = 0.f, s2 = 0.f;
#pragma unroll
        for (int i = 0; i < 8; ++i) {
            float v = acc[i][j] + b;
            v = fmaxf(v, 0.f);
            s1 += v; s2 += v * v;
        }
        sbuf[ty * 128 + cl] = make_float2(s1, s2);
    }
    __syncthreads();
    for (int idx = tid; idx < 512; idx += 256) {
        int ep = idx >> 7, cl = idx & 127;
        float S1 = 0.f, S2 = 0.f;
#pragma unroll
        for (int q = 0; q < 4; ++q) {
            float2 p = sbuf[(ep * 4 + q) * 128 + cl];
            S1 += p.x; S2 += p.y;
        }
        float mean = S1 * (1.f / 32.f);
        float var  = (S2 - 32.f * mean * mean) * (1.f / 31.f);
        float sd   = sqrtf(fmaxf(var, 0.f));
        int e = (row0 >> 5) + ep;
        int f = col0 + cl;
        Z[(size_t)e * TDIM + 1 + f]   = mean;
        Z[(size_t)e * TDIM + 514 + f] = sd;
        if (e >= 256) {
            int j2 = e - 256;
            muT_te[(size_t)(1 + f) * 256 + j2]   = mean;
            muT_te[(size_t)(514 + f) * 256 + j2] = sd;
        }
    }
}

// fallback variant of k_tgt (no Zb)
__global__ __launch_bounds__(256)
void k_tgt_f32(const float* __restrict__ Ttr, const float* __restrict__ Tte,
               float* __restrict__ Z, float* __restrict__ muT_te)
{
    int e = blockIdx.x * 256 + threadIdx.x;
    if (e >= 512) return;
    const float* p = (e < 256) ? (Ttr + (size_t)e * 32) : (Tte + (size_t)(e - 256) * 32);
    float S1 = 0.f, S2 = 0.f;
#pragma unroll
    for (int n = 0; n < 32; ++n) { float v = p[n]; S1 += v; S2 += v * v; }
    float mean = S1 * (1.f / 32.f);
    float var  = (S2 - 32.f * mean * mean) * (1.f / 31.f);
    float sd   = sqrtf(fmaxf(var, 0.f));
    Z[(size_t)e * TDIM + 0]   = mean;
    Z[(size_t)e * TDIM + 513] = sd;
    if (e >= 256) {
        muT_te[(size_t)0 * 256 + (e - 256)]   = mean;
        muT_te[(size_t)513 * 256 + (e - 256)] = sd;
    }
}

// ---------------- Kernel 4: pairwise partial sums -----------------------------
#define TCH 65
__global__ __launch_bounds__(256)
void k_pair(const float* __restrict__ Z, const float* __restrict__ E_tr,
            const float* __restrict__ R_tr, const float* __restrict__ muT_te,
            const float* __restrict__ E_teT, const float* __restrict__ R_teT,
            float* __restrict__ Sp)
{
    __shared__ float Lm[8 * 68], Le[8 * 68], Lr[8 * 68];
    const int tid = threadIdx.x;
    const int i0 = blockIdx.x * 8;
    const int t0 = blockIdx.y * TCH;
    const int tlen = min(TCH, TDIM - t0);

    if (tid < tlen) {
#pragma unroll
        for (int r = 0; r < 8; ++r) {
            size_t off = (size_t)(i0 + r) * TDIM + t0 + tid;
            Lm[r * 68 + tid] = Z[off];
            Le[r * 68 + tid] = E_tr[off];
            Lr[r * 68 + tid] = R_tr[off];
        }
    }
    __syncthreads();

    float S[8];
#pragma unroll
    for (int r = 0; r < 8; ++r) S[r] = 0.f;
    const int j = tid;
    for (int tt = 0; tt < tlen; ++tt) {
        size_t o = (size_t)(t0 + tt) * 256 + j;
        float m2 = muT_te[o], e2 = E_teT[o], r2 = R_teT[o];
#pragma unroll
        for (int r = 0; r < 8; ++r) {
            float m1 = Lm[r * 68 + tt];
            float e1 = Le[r * 68 + tt];
            float r1 = Lr[r * 68 + tt];
            float d = m1 - m2;
            S[r] += e1 * r2 + e2 * r1 + d * d * (r1 + r2);
        }
    }
#pragma unroll
    for (int r = 0; r < 8; ++r)
        Sp[((size_t)blockIdx.y * 256 + i0 + r) * 256 + j] = S[r];
}

// ---------------- Kernel 5: row log_softmax + classes -------------------------
__global__ __launch_bounds__(256)
void k_soft(const float* __restrict__ Sp, const float* __restrict__ Hs_te,
            float* __restrict__ outp)
{
    __shared__ float red[4], red2[4];
    const int i = blockIdx.x, j = threadIdx.x;
    float s = 0.f;
#pragma unroll
    for (int tc = 0; tc < 16; ++tc)
        s += Sp[((size_t)tc * 256 + i) * 256 + j];
    float v = -(0.5f * s + Hs_te[j]);

    float m = v;
#pragma unroll
    for (int o = 32; o > 0; o >>= 1) m = fmaxf(m, __shfl_xor(m, o));
    if ((j & 63) == 0) red[j >> 6] = m;
    __syncthreads();
    m = fmaxf(fmaxf(red[0], red[1]), fmaxf(red[2], red[3]));

    float p = v - m;
    float t = expf(p);
#pragma unroll
    for (int o = 32; o > 0; o >>= 1) t += __shfl_xor(t, o);
    if ((j & 63) == 0) red2[j >> 6] = t;
    __syncthreads();
    t = red2[0] + red2[1] + red2[2] + red2[3];

    outp[(size_t)i * 256 + j] = p - logf(t);
    if (i == 0) outp[65536 + j] = (float)j;
}

extern "C" void kernel_launch(void* const* d_in, const int* in_sizes, int n_in,
                              void* d_out, int out_size, void* d_ws, size_t ws_size,
                              hipStream_t stream)
{
    const float* tri = (const float*)d_in[0];
    const float* trt = (const float*)d_in[1];
    const float* tei = (const float*)d_in[2];
    const float* tet = (const float*)d_in[3];
    const float* Wfe = (const float*)d_in[4];
    const float* bfe = (const float*)d_in[5];
    const float* Wlv = (const float*)d_in[6];
    const float* blv = (const float*)d_in[7];
    float* outp = (float*)d_out;

    float* Z     = (float*)d_ws;                 // 512*1026 fp32
    float* E_tr  = Z + (size_t)512 * TDIM;
    float* R_tr  = E_tr + (size_t)256 * TDIM;
    float* muT   = R_tr + (size_t)256 * TDIM;
    float* E_teT = muT + (size_t)TDIM * 256;
    float* R_teT = E_teT + (size_t)TDIM * 256;
    float* Hs_te = R_teT + (size_t)TDIM * 256;   // 256 (+pad to 1024B)
    float* Sp    = Hs_te + 256;                  // 16*256*256 fp32 = 4,194,304 B
    float* endf  = Sp + (size_t)16 * 256 * 256;  // ws + 11,549,696 B
    unsigned short* Abf = (unsigned short*)endf;          // 16384*512 bf16 = 16 MB
    unsigned short* Wt  = Abf + (size_t)16384 * 512;      // 512*512 bf16

    // Wlt/Zb alias the Sp region: consumed by k_lv_mfma strictly before k_pair writes Sp.
    unsigned short* Wlt = (unsigned short*)Sp;                       // NP*KP bf16 = 2,433,024 B
    unsigned short* Zb  = (unsigned short*)((char*)Sp + 2433024);    // 512*KP bf16 = 1,081,344 B

    const size_t need = 11549696ull + 16777216ull + 524288ull;       // 28,851,200 B
    const bool fast = (ws_size >= need);

    hipMemsetAsync(Hs_te, 0, 256 * sizeof(float), stream);
    if (fast) {
        k_cvta  <<<4096, 256, 0, stream>>>(tri, tei, Abf);
        k_cvtw  <<<dim3(16, 16), 256, 0, stream>>>(Wfe, Wt);
        k_cvtwlv<<<dim3(36, 33), 256, 0, stream>>>(Wlv, Wlt);
        k_fe_mfma<<<dim3(4, 128), 256, 0, stream>>>(Abf, Wt, bfe, Z, Zb, muT);
        k_tgt   <<<2, 256, 0, stream>>>(trt, tet, Z, Zb, muT);
        k_lv_mfma<<<dim3(9, 4), 256, 0, stream>>>(Zb, Wlt, blv, E_tr, R_tr, E_teT, R_teT, Hs_te);
    } else {
        k_fe_f32<<<dim3(4, 128), 256, 0, stream>>>(tri, tei, Wfe, bfe, Z, muT);
        k_tgt_f32<<<2, 256, 0, stream>>>(trt, tet, Z, muT);
        k_lv    <<<dim3(17, 8), 256, 0, stream>>>(Z, Wlv, blv, E_tr, R_tr, E_teT, R_teT, Hs_te);
    }
    k_pair<<<dim3(32, 16), 256, 0, stream>>>(Z, E_tr, R_tr, muT, E_teT, R_teT, Sp);
    k_soft<<<256, 256, 0, stream>>>(Sp, Hs_te, outp);
}

// Round 4
// 170.920 us; speedup vs baseline: 1.9328x; 1.1903x over previous
//
#include <hip/hip_runtime.h>
#include <math.h>

#define TDIM 1026
#define KP 1056          // K padded for LV GEMM (33 * 32)
#define NP 1152          // N padded for LV GEMM (9 * 128)
#define KSPLIT 7

typedef __attribute__((ext_vector_type(8))) short bf16x8;
typedef __attribute__((ext_vector_type(4))) float f32x4;

// ---- fp32 -> bf16 RNE helpers ------------------------------------------------
__device__ inline unsigned int pk_bf16(float a, float b) {
    unsigned int ua = __float_as_uint(a), ub = __float_as_uint(b);
    ua = (ua + 0x7FFFu + ((ua >> 16) & 1u)) >> 16;
    ub = (ub + 0x7FFFu + ((ub >> 16) & 1u)) & 0xFFFF0000u;
    return ua | ub;
}
__device__ inline unsigned short f2bf(float a) {
    unsigned int ua = __float_as_uint(a);
    return (unsigned short)((ua + 0x7FFFu + ((ua >> 16) & 1u)) >> 16);
}

// ---- convert A (train rows 0..8191, test rows 8192..16383) to bf16 ----------
__global__ __launch_bounds__(256)
void k_cvta(const float* __restrict__ tri, const float* __restrict__ tei,
            unsigned short* __restrict__ Abf)
{
    size_t g = ((size_t)blockIdx.x * 256 + threadIdx.x) * 8;
    const float* src = (g < 4194304) ? (tri + g) : (tei + (g - 4194304));
    float4 v0 = *(const float4*)(src);
    float4 v1 = *(const float4*)(src + 4);
    uint4 o;
    o.x = pk_bf16(v0.x, v0.y); o.y = pk_bf16(v0.z, v0.w);
    o.z = pk_bf16(v1.x, v1.y); o.w = pk_bf16(v1.z, v1.w);
    *(uint4*)(Abf + g) = o;
}

// ---- convert + transpose W_fe (512x512, [k][n]) -> Wt bf16 [n][k] -----------
__global__ __launch_bounds__(256)
void k_cvtw(const float* __restrict__ W, unsigned short* __restrict__ Wt)
{
    __shared__ float T[32][33];
    const int k0 = blockIdx.y * 32, n0 = blockIdx.x * 32;
    const int t = threadIdx.x;
    {
        int ky = t >> 3, nx = (t & 7) * 4;
        float4 v = *(const float4*)(W + (size_t)(k0 + ky) * 512 + n0 + nx);
        T[nx + 0][ky] = v.x; T[nx + 1][ky] = v.y;
        T[nx + 2][ky] = v.z; T[nx + 3][ky] = v.w;
    }
    __syncthreads();
    {
        int ny = t >> 3, kx = (t & 7) * 4;
        ushort4 o;
        o.x = f2bf(T[ny][kx + 0]); o.y = f2bf(T[ny][kx + 1]);
        o.z = f2bf(T[ny][kx + 2]); o.w = f2bf(T[ny][kx + 3]);
        *(ushort4*)(Wt + (size_t)(n0 + ny) * 512 + k0 + kx) = o;
    }
}

// ---- convert + transpose W_lv (1026x1026 [k][n]) -> Wlt bf16 [n][KP], padded -
__global__ __launch_bounds__(256)
void k_cvtwlv(const float* __restrict__ W, unsigned short* __restrict__ Wlt)
{
    __shared__ float T[32][33];
    const int n0 = blockIdx.x * 32, k0 = blockIdx.y * 32;
    const int t = threadIdx.x;
    {
        int ky = t >> 3, nx = (t & 7) * 4;
#pragma unroll
        for (int i = 0; i < 4; ++i) {
            float v = 0.f;
            if (k0 + ky < TDIM && n0 + nx + i < TDIM)
                v = W[(size_t)(k0 + ky) * TDIM + n0 + nx + i];
            T[nx + i][ky] = v;
        }
    }
    __syncthreads();
    {
        int ny = t >> 3, kx = (t & 7) * 4;
        ushort4 o;
        o.x = f2bf(T[ny][kx + 0]); o.y = f2bf(T[ny][kx + 1]);
        o.z = f2bf(T[ny][kx + 2]); o.w = f2bf(T[ny][kx + 3]);
        *(ushort4*)(Wlt + (size_t)(n0 + ny) * KP + k0 + kx) = o;
    }
}

// ---- Kernel 1 (fast): bf16 MFMA FE GEMM + bias/relu + per-episode stats -----
__global__ __launch_bounds__(256)
void k_fe_mfma(const unsigned short* __restrict__ Abf,
               const unsigned short* __restrict__ Wt,
               const float* __restrict__ bfe, float* __restrict__ Z,
               unsigned short* __restrict__ Zb, float* __restrict__ muT_te)
{
    __shared__ unsigned short As[128 * 40];
    __shared__ unsigned short Bs[128 * 40];
    __shared__ float2 sbuf[4 * 128];

    const int tid  = threadIdx.x;
    const int lane = tid & 63;
    const int wave = tid >> 6;
    const int wr = wave >> 1, wc = wave & 1;
    const int m = lane & 15, quad = lane >> 4;
    const int col0 = blockIdx.x * 128;
    const int row0 = blockIdx.y * 128;

    f32x4 acc[4][4];
#pragma unroll
    for (int i = 0; i < 4; ++i)
#pragma unroll
        for (int j = 0; j < 4; ++j) acc[i][j] = (f32x4){0.f, 0.f, 0.f, 0.f};

    const int srow = tid >> 2;
    const int skc  = tid & 3;

    for (int k0 = 0; k0 < 512; k0 += 32) {
#pragma unroll
        for (int s = 0; s < 2; ++s) {
            int row = srow + s * 64;
            uint4 va = *(const uint4*)(Abf + (size_t)(row0 + row) * 512 + k0 + skc * 8);
            uint4 vb = *(const uint4*)(Wt  + (size_t)(col0 + row) * 512 + k0 + skc * 8);
            *(uint4*)(As + row * 40 + skc * 8) = va;
            *(uint4*)(Bs + row * 40 + skc * 8) = vb;
        }
        __syncthreads();
        bf16x8 af[4], bfr[4];
#pragma unroll
        for (int t2 = 0; t2 < 4; ++t2) {
            af[t2]  = *(const bf16x8*)(As + (wr * 64 + t2 * 16 + m) * 40 + quad * 8);
            bfr[t2] = *(const bf16x8*)(Bs + (wc * 64 + t2 * 16 + m) * 40 + quad * 8);
        }
#pragma unroll
        for (int ti = 0; ti < 4; ++ti)
#pragma unroll
            for (int tj = 0; tj < 4; ++tj)
                acc[ti][tj] = __builtin_amdgcn_mfma_f32_16x16x32_bf16(
                    af[ti], bfr[tj], acc[ti][tj], 0, 0, 0);
        __syncthreads();
    }

#pragma unroll
    for (int ep = 0; ep < 2; ++ep) {
#pragma unroll
        for (int tj = 0; tj < 4; ++tj) {
            int colL = wc * 64 + tj * 16 + m;
            float b = bfe[col0 + colL];
            float s1 = 0.f, s2 = 0.f;
#pragma unroll
            for (int p = 0; p < 2; ++p) {
                int ti = ep * 2 + p;
#pragma unroll
                for (int r = 0; r < 4; ++r) {
                    float v = fmaxf(acc[ti][tj][r] + b, 0.f);
                    s1 += v; s2 += v * v;
                }
            }
            s1 += __shfl_xor(s1, 16); s1 += __shfl_xor(s1, 32);
            s2 += __shfl_xor(s2, 16); s2 += __shfl_xor(s2, 32);
            if (lane < 16) sbuf[(wr * 2 + ep) * 128 + colL] = make_float2(s1, s2);
        }
    }
    __syncthreads();
    for (int idx = tid; idx < 512; idx += 256) {
        int ep = idx >> 7, cl = idx & 127;
        float2 pr = sbuf[ep * 128 + cl];
        float mean = pr.x * (1.f / 32.f);
        float var  = (pr.y - 32.f * mean * mean) * (1.f / 31.f);   // ddof=1
        float sd   = sqrtf(fmaxf(var, 0.f));
        int e = blockIdx.y * 4 + ep;
        int f = col0 + cl;
        Z[(size_t)e * TDIM + 1 + f]   = mean;
        Z[(size_t)e * TDIM + 514 + f] = sd;
        Zb[(size_t)e * KP + 1 + f]    = f2bf(mean);
        Zb[(size_t)e * KP + 514 + f]  = f2bf(sd);
        if (e >= 256) {
            int j2 = e - 256;
            muT_te[(size_t)(1 + f) * 256 + j2]   = mean;
            muT_te[(size_t)(514 + f) * 256 + j2] = sd;
        }
    }
}

// ---------------- Kernel 2: targets column stats + Zb pad zeroing -------------
__global__ __launch_bounds__(256)
void k_tgt(const float* __restrict__ Ttr, const float* __restrict__ Tte,
           float* __restrict__ Z, unsigned short* __restrict__ Zb,
           float* __restrict__ muT_te)
{
    int e = blockIdx.x * 256 + threadIdx.x;
    if (e >= 512) return;
    const float* p = (e < 256) ? (Ttr + (size_t)e * 32) : (Tte + (size_t)(e - 256) * 32);
    float S1 = 0.f, S2 = 0.f;
#pragma unroll
    for (int n = 0; n < 32; ++n) { float v = p[n]; S1 += v; S2 += v * v; }
    float mean = S1 * (1.f / 32.f);
    float var  = (S2 - 32.f * mean * mean) * (1.f / 31.f);
    float sd   = sqrtf(fmaxf(var, 0.f));
    Z[(size_t)e * TDIM + 0]   = mean;
    Z[(size_t)e * TDIM + 513] = sd;
    Zb[(size_t)e * KP + 0]    = f2bf(mean);
    Zb[(size_t)e * KP + 513]  = f2bf(sd);
#pragma unroll
    for (int c = TDIM; c < KP; ++c) Zb[(size_t)e * KP + c] = 0;   // K pad (ws re-poisoned)
    if (e >= 256) {
        muT_te[(size_t)0 * 256 + (e - 256)]   = mean;
        muT_te[(size_t)513 * 256 + (e - 256)] = sd;
    }
}

// ---- Kernel 3a (fast): bf16 MFMA LV GEMM, split-K=7, raw fp32 partials -------
// Grid (9, 4, 7). Block p handles K-iters {5,5,5,5,5,4,4} of 32. Partial C tile
// (128x128 fp32) stored raw to Cacc[p] (512x1152); reduced in k_lv_ep.
__global__ __launch_bounds__(256)
void k_lv_mfma(const unsigned short* __restrict__ Zb,
               const unsigned short* __restrict__ Wlt,
               float* __restrict__ Cacc)
{
    __shared__ unsigned short As[128 * 40];
    __shared__ unsigned short Bs[128 * 40];

    const int tid  = threadIdx.x;
    const int lane = tid & 63;
    const int wave = tid >> 6;
    const int wr = wave >> 1, wc = wave & 1;
    const int m = lane & 15, quad = lane >> 4;
    const int col0 = blockIdx.x * 128;
    const int row0 = blockIdx.y * 128;
    const int p    = blockIdx.z;
    const int it0  = (p < 5) ? p * 5 : 25 + (p - 5) * 4;
    const int itn  = (p < 5) ? 5 : 4;

    f32x4 acc[4][4];
#pragma unroll
    for (int i = 0; i < 4; ++i)
#pragma unroll
        for (int j = 0; j < 4; ++j) acc[i][j] = (f32x4){0.f, 0.f, 0.f, 0.f};

    const int srow = tid >> 2;
    const int skc  = tid & 3;

    for (int it = it0; it < it0 + itn; ++it) {
        int k0 = it * 32;
#pragma unroll
        for (int s = 0; s < 2; ++s) {
            int row = srow + s * 64;
            uint4 va = *(const uint4*)(Zb  + (size_t)(row0 + row) * KP + k0 + skc * 8);
            uint4 vb = *(const uint4*)(Wlt + (size_t)(col0 + row) * KP + k0 + skc * 8);
            *(uint4*)(As + row * 40 + skc * 8) = va;
            *(uint4*)(Bs + row * 40 + skc * 8) = vb;
        }
        __syncthreads();
        bf16x8 af[4], bfr[4];
#pragma unroll
        for (int t2 = 0; t2 < 4; ++t2) {
            af[t2]  = *(const bf16x8*)(As + (wr * 64 + t2 * 16 + m) * 40 + quad * 8);
            bfr[t2] = *(const bf16x8*)(Bs + (wc * 64 + t2 * 16 + m) * 40 + quad * 8);
        }
#pragma unroll
        for (int ti = 0; ti < 4; ++ti)
#pragma unroll
            for (int tj = 0; tj < 4; ++tj)
                acc[ti][tj] = __builtin_amdgcn_mfma_f32_16x16x32_bf16(
                    af[ti], bfr[tj], acc[ti][tj], 0, 0, 0);
        __syncthreads();
    }

    float* C = Cacc + (size_t)p * 512 * NP;
#pragma unroll
    for (int ti = 0; ti < 4; ++ti)
#pragma unroll
        for (int tj = 0; tj < 4; ++tj) {
            int c = col0 + wc * 64 + tj * 16 + m;
#pragma unroll
            for (int r = 0; r < 4; ++r) {
                int rg = row0 + wr * 64 + ti * 16 + quad * 4 + r;
                C[(size_t)rg * NP + c] = acc[ti][tj][r];
            }
        }
}

// ---- Kernel 3b: reduce 7 partials + bias + clip + exp; tr coalesced, te via
// LDS transpose; H per te-row via shfl + atomicAdd. Grid (33, 16), block 256.
__global__ __launch_bounds__(256)
void k_lv_ep(const float* __restrict__ Cacc, const float* __restrict__ blv,
             float* __restrict__ E_tr, float* __restrict__ R_tr,
             float* __restrict__ E_teT, float* __restrict__ R_teT,
             float* __restrict__ Hs_te)
{
    __shared__ float Et[32][33], Rt[32][33];
    const int t = threadIdx.x;
    const int rl = t >> 3;            // 0..31 local row
    const int ci = t & 7;             // 0..7  -> 4 cols each
    const int r  = blockIdx.y * 32 + rl;
    const int c0 = blockIdx.x * 32 + ci * 4;
    const bool is_te = (blockIdx.y >= 8);

    float4 s = make_float4(0.f, 0.f, 0.f, 0.f);
#pragma unroll
    for (int p = 0; p < KSPLIT; ++p) {
        float4 v = *(const float4*)(Cacc + (size_t)p * 512 * NP + (size_t)r * NP + c0);
        s.x += v.x; s.y += v.y; s.z += v.z; s.w += v.w;
    }
    float sv[4] = {s.x, s.y, s.z, s.w};
    float lv[4], E[4], R[4];
#pragma unroll
    for (int q = 0; q < 4; ++q) {
        int c = c0 + q;
        float b = (c < TDIM) ? blv[c] : 0.f;
        float x = fminf(fmaxf(sv[q] + b, -9.f), -2.f);
        lv[q] = x; E[q] = expf(x); R[q] = expf(-x);
    }

    if (!is_te) {
        // rows 0..255: coalesced row-major stores (8B-aligned -> float2 pairs)
        if (c0 + 1 < TDIM) {
            *(float2*)(E_tr + (size_t)r * TDIM + c0) = make_float2(E[0], E[1]);
            *(float2*)(R_tr + (size_t)r * TDIM + c0) = make_float2(R[0], R[1]);
        }
        if (c0 + 3 < TDIM) {
            *(float2*)(E_tr + (size_t)r * TDIM + c0 + 2) = make_float2(E[2], E[3]);
            *(float2*)(R_tr + (size_t)r * TDIM + c0 + 2) = make_float2(R[2], R[3]);
        }
    } else {
        float h = 0.f;
#pragma unroll
        for (int q = 0; q < 4; ++q) {
            Et[ci * 4 + q][rl] = E[q];
            Rt[ci * 4 + q][rl] = R[q];
            if (c0 + q < TDIM) h += lv[q];
        }
        h += __shfl_xor(h, 1); h += __shfl_xor(h, 2); h += __shfl_xor(h, 4);
        if (ci == 0) atomicAdd(Hs_te + (r - 256), h);
        __syncthreads();
        int cl = t >> 3, ri = (t & 7) * 4;
        int c = blockIdx.x * 32 + cl;
        if (c < TDIM) {
            int rbase = (blockIdx.y - 8) * 32 + ri;
            *(float4*)(E_teT + (size_t)c * 256 + rbase) =
                make_float4(Et[cl][ri], Et[cl][ri + 1], Et[cl][ri + 2], Et[cl][ri + 3]);
            *(float4*)(R_teT + (size_t)c * 256 + rbase) =
                make_float4(Rt[cl][ri], Rt[cl][ri + 1], Rt[cl][ri + 2], Rt[cl][ri + 3]);
        }
    }
}

// ---- Kernel 3 (fallback, fp32) ----------------------------------------------
__global__ __launch_bounds__(256)
void k_lv(const float* __restrict__ Z, const float* __restrict__ Wlv,
          const float* __restrict__ blv,
          float* __restrict__ E_tr, float* __restrict__ R_tr,
          float* __restrict__ E_teT, float* __restrict__ R_teT,
          float* __restrict__ Hs_te)
{
    __shared__ float Ast[16 * 68];
    __shared__ float Bs[16 * 68];
    const int tid = threadIdx.x;
    const int tx = tid & 15;
    const int ty = tid >> 4;
    const int col0 = blockIdx.x * 64;
    const int row0 = blockIdx.y * 64;

    float acc[4][4];
#pragma unroll
    for (int i = 0; i < 4; ++i)
#pragma unroll
        for (int j = 0; j < 4; ++j) acc[i][j] = 0.f;

    for (int k0 = 0; k0 < TDIM; k0 += 16) {
        {
            int row = tid >> 2, kp = tid & 3;
            const float* src = Z + (size_t)(row0 + row) * TDIM + k0 + kp * 4;
            float x0 = 0.f, x1 = 0.f, x2 = 0.f, x3 = 0.f;
            if (k0 + kp * 4 + 1 < TDIM) { float2 v = *(const float2*)(src);     x0 = v.x; x1 = v.y; }
            if (k0 + kp * 4 + 3 < TDIM) { float2 v = *(const float2*)(src + 2); x2 = v.x; x3 = v.y; }
            Ast[(kp * 4 + 0) * 68 + row] = x0;
            Ast[(kp * 4 + 1) * 68 + row] = x1;
            Ast[(kp * 4 + 2) * 68 + row] = x2;
            Ast[(kp * 4 + 3) * 68 + row] = x3;
        }
        {
            int kk = tid >> 4, cg = tid & 15;
#pragma unroll
            for (int c = 0; c < 4; ++c) {
                int col = col0 + cg * 4 + c;
                float v = 0.f;
                if (k0 + kk < TDIM && col < TDIM)
                    v = Wlv[(size_t)(k0 + kk) * TDIM + col];
                Bs[kk * 68 + cg * 4 + c] = v;
            }
        }
        __syncthreads();
#pragma unroll
        for (int kk = 0; kk < 16; ++kk) {
            float4 a = *(const float4*)(Ast + kk * 68 + ty * 4);
            float4 b = *(const float4*)(Bs + kk * 68 + tx * 4);
            float av[4] = {a.x, a.y, a.z, a.w};
            float bv[4] = {b.x, b.y, b.z, b.w};
#pragma unroll
            for (int i = 0; i < 4; ++i)
#pragma unroll
                for (int j = 0; j < 4; ++j)
                    acc[i][j] = fmaf(av[i], bv[j], acc[i][j]);
        }
        __syncthreads();
    }

    float hpart[4] = {0.f, 0.f, 0.f, 0.f};
#pragma unroll
    for (int i = 0; i < 4; ++i) {
        int r = row0 + ty * 4 + i;
#pragma unroll
        for (int j = 0; j < 4; ++j) {
            int c = col0 + tx * 4 + j;
            if (c < TDIM) {
                float lv = acc[i][j] + blv[c];
                lv = fminf(fmaxf(lv, -9.f), -2.f);
                float E = expf(lv);
                float R = expf(-lv);
                if (r < 256) {
                    E_tr[(size_t)r * TDIM + c] = E;
                    R_tr[(size_t)r * TDIM + c] = R;
                } else {
                    E_teT[(size_t)c * 256 + (r - 256)] = E;
                    R_teT[(size_t)c * 256 + (r - 256)] = R;
                    hpart[i] += lv;
                }
            }
        }
    }
    if (row0 >= 256) {
        __syncthreads();
        float* hbuf = Ast;
#pragma unroll
        for (int i = 0; i < 4; ++i) hbuf[(ty * 4 + i) * 16 + tx] = hpart[i];
        __syncthreads();
        if (tid < 64) {
            float s = 0.f;
#pragma unroll
            for (int x = 0; x < 16; ++x) s += hbuf[tid * 16 + x];
            atomicAdd(Hs_te + (row0 - 256 + tid), s);
        }
    }
}

// ---- Kernel 1 (fallback, fp32) ----------------------------------------------
__global__ __launch_bounds__(256)
void k_fe_f32(const float* __restrict__ Atr, const float* __restrict__ Ate,
              const float* __restrict__ Wfe, const float* __restrict__ bfe,
              float* __restrict__ Z, float* __restrict__ muT_te)
{
    __shared__ float lds[4224];
    float* Ast = lds;
    float* Bs  = lds + 2112;

    const int tid = threadIdx.x;
    const int tx = tid & 15;
    const int ty = tid >> 4;
    const int col0 = blockIdx.x * 128;
    const int row0 = blockIdx.y * 128;
    const float* A = (row0 < 8192) ? Atr : Ate;
    const int ar0 = (row0 < 8192) ? row0 : (row0 - 8192);

    float acc[8][8];
#pragma unroll
    for (int i = 0; i < 8; ++i)
#pragma unroll
        for (int j = 0; j < 8; ++j) acc[i][j] = 0.f;

    for (int k0 = 0; k0 < 512; k0 += 16) {
#pragma unroll
        for (int s = 0; s < 2; ++s) {
            int u = tid + s * 256;
            int row = u >> 2, q = u & 3;
            float4 v = *(const float4*)(A + (size_t)(ar0 + row) * 512 + k0 + q * 4);
            Ast[(q * 4 + 0) * 132 + row] = v.x;
            Ast[(q * 4 + 1) * 132 + row] = v.y;
            Ast[(q * 4 + 2) * 132 + row] = v.z;
            Ast[(q * 4 + 3) * 132 + row] = v.w;
        }
#pragma unroll
        for (int s = 0; s < 2; ++s) {
            int u = tid + s * 256;
            int kk = u >> 5, c8 = u & 31;
            float4 v = *(const float4*)(Wfe + (size_t)(k0 + kk) * 512 + col0 + c8 * 4);
            *(float4*)(Bs + kk * 132 + c8 * 4) = v;
        }
        __syncthreads();
#pragma unroll
        for (int kk = 0; kk < 16; ++kk) {
            float4 a0 = *(const float4*)(Ast + kk * 132 + ty * 8);
            float4 a1 = *(const float4*)(Ast + kk * 132 + ty * 8 + 4);
            float4 b0 = *(const float4*)(Bs + kk * 132 + tx * 4);
            float4 b1 = *(const float4*)(Bs + kk * 132 + 64 + tx * 4);
            float av[8] = {a0.x, a0.y, a0.z, a0.w, a1.x, a1.y, a1.z, a1.w};
            float bv[8] = {b0.x, b0.y, b0.z, b0.w, b1.x, b1.y, b1.z, b1.w};
#pragma unroll
            for (int i = 0; i < 8; ++i)
#pragma unroll
                for (int j = 0; j < 8; ++j)
                    acc[i][j] = fmaf(av[i], bv[j], acc[i][j]);
        }
        __syncthreads();
    }

    float2* sbuf = (float2*)lds;
#pragma unroll
    for (int j = 0; j < 8; ++j) {
        int cl = (j < 4) ? (tx * 4 + j) : (64 + tx * 4 + (j - 4));
        float b = bfe[col0 + cl];
        float s1 = 0.f, s2 = 0.f;
#pragma unroll
        for (int i = 0; i < 8; ++i) {
            float v = acc[i][j] + b;
            v = fmaxf(v, 0.f);
            s1 += v; s2 += v * v;
        }
        sbuf[ty * 128 + cl] = make_float2(s1, s2);
    }
    __syncthreads();
    for (int idx = tid; idx < 512; idx += 256) {
        int ep = idx >> 7, cl = idx & 127;
        float S1 = 0.f, S2 = 0.f;
#pragma unroll
        for (int q = 0; q < 4; ++q) {
            float2 p = sbuf[(ep * 4 + q) * 128 + cl];
            S1 += p.x; S2 += p.y;
        }
        float mean = S1 * (1.f / 32.f);
        float var  = (S2 - 32.f * mean * mean) * (1.f / 31.f);
        float sd   = sqrtf(fmaxf(var, 0.f));
        int e = (row0 >> 5) + ep;
        int f = col0 + cl;
        Z[(size_t)e * TDIM + 1 + f]   = mean;
        Z[(size_t)e * TDIM + 514 + f] = sd;
        if (e >= 256) {
            int j2 = e - 256;
            muT_te[(size_t)(1 + f) * 256 + j2]   = mean;
            muT_te[(size_t)(514 + f) * 256 + j2] = sd;
        }
    }
}

// fallback variant of k_tgt (no Zb)
__global__ __launch_bounds__(256)
void k_tgt_f32(const float* __restrict__ Ttr, const float* __restrict__ Tte,
               float* __restrict__ Z, float* __restrict__ muT_te)
{
    int e = blockIdx.x * 256 + threadIdx.x;
    if (e >= 512) return;
    const float* p = (e < 256) ? (Ttr + (size_t)e * 32) : (Tte + (size_t)(e - 256) * 32);
    float S1 = 0.f, S2 = 0.f;
#pragma unroll
    for (int n = 0; n < 32; ++n) { float v = p[n]; S1 += v; S2 += v * v; }
    float mean = S1 * (1.f / 32.f);
    float var  = (S2 - 32.f * mean * mean) * (1.f / 31.f);
    float sd   = sqrtf(fmaxf(var, 0.f));
    Z[(size_t)e * TDIM + 0]   = mean;
    Z[(size_t)e * TDIM + 513] = sd;
    if (e >= 256) {
        muT_te[(size_t)0 * 256 + (e - 256)]   = mean;
        muT_te[(size_t)513 * 256 + (e - 256)] = sd;
    }
}

// ---------------- Kernel 4: pairwise partial sums -----------------------------
#define TCH 65
__global__ __launch_bounds__(256)
void k_pair(const float* __restrict__ Z, const float* __restrict__ E_tr,
            const float* __restrict__ R_tr, const float* __restrict__ muT_te,
            const float* __restrict__ E_teT, const float* __restrict__ R_teT,
            float* __restrict__ Sp)
{
    __shared__ float Lm[8 * 68], Le[8 * 68], Lr[8 * 68];
    const int tid = threadIdx.x;
    const int i0 = blockIdx.x * 8;
    const int t0 = blockIdx.y * TCH;
    const int tlen = min(TCH, TDIM - t0);

    if (tid < tlen) {
#pragma unroll
        for (int r = 0; r < 8; ++r) {
            size_t off = (size_t)(i0 + r) * TDIM + t0 + tid;
            Lm[r * 68 + tid] = Z[off];
            Le[r * 68 + tid] = E_tr[off];
            Lr[r * 68 + tid] = R_tr[off];
        }
    }
    __syncthreads();

    float S[8];
#pragma unroll
    for (int r = 0; r < 8; ++r) S[r] = 0.f;
    const int j = tid;
    for (int tt = 0; tt < tlen; ++tt) {
        size_t o = (size_t)(t0 + tt) * 256 + j;
        float m2 = muT_te[o], e2 = E_teT[o], r2 = R_teT[o];
#pragma unroll
        for (int r = 0; r < 8; ++r) {
            float m1 = Lm[r * 68 + tt];
            float e1 = Le[r * 68 + tt];
            float r1 = Lr[r * 68 + tt];
            float d = m1 - m2;
            S[r] += e1 * r2 + e2 * r1 + d * d * (r1 + r2);
        }
    }
#pragma unroll
    for (int r = 0; r < 8; ++r)
        Sp[((size_t)blockIdx.y * 256 + i0 + r) * 256 + j] = S[r];
}

// ---------------- Kernel 5: row log_softmax + classes -------------------------
__global__ __launch_bounds__(256)
void k_soft(const float* __restrict__ Sp, const float* __restrict__ Hs_te,
            float* __restrict__ outp)
{
    __shared__ float red[4], red2[4];
    const int i = blockIdx.x, j = threadIdx.x;
    float s = 0.f;
#pragma unroll
    for (int tc = 0; tc < 16; ++tc)
        s += Sp[((size_t)tc * 256 + i) * 256 + j];
    float v = -(0.5f * s + Hs_te[j]);

    float m = v;
#pragma unroll
    for (int o = 32; o > 0; o >>= 1) m = fmaxf(m, __shfl_xor(m, o));
    if ((j & 63) == 0) red[j >> 6] = m;
    __syncthreads();
    m = fmaxf(fmaxf(red[0], red[1]), fmaxf(red[2], red[3]));

    float p = v - m;
    float t = expf(p);
#pragma unroll
    for (int o = 32; o > 0; o >>= 1) t += __shfl_xor(t, o);
    if ((j & 63) == 0) red2[j >> 6] = t;
    __syncthreads();
    t = red2[0] + red2[1] + red2[2] + red2[3];

    outp[(size_t)i * 256 + j] = p - logf(t);
    if (i == 0) outp[65536 + j] = (float)j;
}

extern "C" void kernel_launch(void* const* d_in, const int* in_sizes, int n_in,
                              void* d_out, int out_size, void* d_ws, size_t ws_size,
                              hipStream_t stream)
{
    const float* tri = (const float*)d_in[0];
    const float* trt = (const float*)d_in[1];
    const float* tei = (const float*)d_in[2];
    const float* tet = (const float*)d_in[3];
    const float* Wfe = (const float*)d_in[4];
    const float* bfe = (const float*)d_in[5];
    const float* Wlv = (const float*)d_in[6];
    const float* blv = (const float*)d_in[7];
    float* outp = (float*)d_out;

    float* Z     = (float*)d_ws;                 // 512*1026 fp32
    float* E_tr  = Z + (size_t)512 * TDIM;
    float* R_tr  = E_tr + (size_t)256 * TDIM;
    float* muT   = R_tr + (size_t)256 * TDIM;
    float* E_teT = muT + (size_t)TDIM * 256;
    float* R_teT = E_teT + (size_t)TDIM * 256;
    float* Hs_te = R_teT + (size_t)TDIM * 256;   // 256
    float* Sp    = Hs_te + 256;                  // 16*256*256 fp32 = 4,194,304 B
    float* endf  = Sp + (size_t)16 * 256 * 256;  // ws + 11,549,696 B
    unsigned short* Abf = (unsigned short*)endf;          // 16 MB region
    unsigned short* Wt  = Abf + (size_t)16384 * 512;      // 512*512 bf16

    // Wlt/Zb alias the Sp region (consumed before k_pair writes Sp).
    unsigned short* Wlt = (unsigned short*)Sp;                       // NP*KP bf16 = 2,433,024 B
    unsigned short* Zb  = (unsigned short*)((char*)Sp + 2433024);    // 512*KP bf16 = 1,081,344 B
    // Cacc aliases the Abf region (dead after k_fe_mfma): 7*512*1152*4 = 16,515,072 B <= 16 MB region
    float* Cacc = (float*)Abf;

    const size_t need = 11549696ull + 16777216ull + 524288ull;       // 28,851,200 B
    const bool fast = (ws_size >= need);

    hipMemsetAsync(Hs_te, 0, 256 * sizeof(float), stream);
    if (fast) {
        k_cvta  <<<4096, 256, 0, stream>>>(tri, tei, Abf);
        k_cvtw  <<<dim3(16, 16), 256, 0, stream>>>(Wfe, Wt);
        k_cvtwlv<<<dim3(36, 33), 256, 0, stream>>>(Wlv, Wlt);
        k_fe_mfma<<<dim3(4, 128), 256, 0, stream>>>(Abf, Wt, bfe, Z, Zb, muT);
        k_tgt   <<<2, 256, 0, stream>>>(trt, tet, Z, Zb, muT);
        k_lv_mfma<<<dim3(9, 4, KSPLIT), 256, 0, stream>>>(Zb, Wlt, Cacc);
        k_lv_ep <<<dim3(33, 16), 256, 0, stream>>>(Cacc, blv, E_tr, R_tr, E_teT, R_teT, Hs_te);
    } else {
        k_fe_f32<<<dim3(4, 128), 256, 0, stream>>>(tri, tei, Wfe, bfe, Z, muT);
        k_tgt_f32<<<2, 256, 0, stream>>>(trt, tet, Z, muT);
        k_lv    <<<dim3(17, 8), 256, 0, stream>>>(Z, Wlv, blv, E_tr, R_tr, E_teT, R_teT, Hs_te);
    }
    k_pair<<<dim3(32, 16), 256, 0, stream>>>(Z, E_tr, R_tr, muT, E_teT, R_teT, Sp);
    k_soft<<<256, 256, 0, stream>>>(Sp, Hs_te, outp);
}